// Round 1
// baseline (2008.378 us; speedup 1.0000x reference)
//
#include <hip/hip_runtime.h>
#include <hip/hip_bf16.h>

// Problem constants (from reference)
#define NGRID  65160
#define NMESH  10242
#define NTOT   75402      // NGRID + NMESH
#define FEAT   156
#define FI_    3
#define KENC   159        // FEAT + FI_
#define HD     128
#define OUTD   78
#define BB     2
#define NE_ENC 130320
#define NE_PROC 81920
#define NE_DEC 195480

// ---------------------------------------------------------------------------
// Degree / normalization kernels
// ---------------------------------------------------------------------------
__global__ void fill1_kernel(float* __restrict__ p, int n) {
    int i = blockIdx.x * 256 + threadIdx.x;
    if (i < n) p[i] = 1.0f;   // self-loop contributes 1 to every node's degree
}

__global__ void count_edges_kernel(const int* __restrict__ dst, float* __restrict__ deg, int ne) {
    int e = blockIdx.x * 256 + threadIdx.x;
    if (e < ne) atomicAdd(&deg[dst[e]], 1.0f);
}

__global__ void rsqrt_kernel(float* __restrict__ p, int n) {
    int i = blockIdx.x * 256 + threadIdx.x;
    if (i < n) p[i] = rsqrtf(p[i]);
}

// ---------------------------------------------------------------------------
// Row-wise GEMM: Out[row] = act(A[row] @ W + bias)
// 64 rows x NOUT cols per 256-thread block, 8x4 register micro-tile.
// A rows staged in LDS (so in-place A==Out is safe; block owns disjoint rows).
// MODE 0: A from A0 (rows < split) / A1 (rows >= split, if A1 != null)
// MODE 1: fused encoder concat loader: [X | init_grid] for grid rows,
//         [0 | init_mesh] for mesh rows. (K = 159)
// ---------------------------------------------------------------------------
template<int K, int NOUT, int MODE, int RELU>
__global__ __launch_bounds__(256)
void gemm_rows(const float* __restrict__ A0, long long a0_bs,
               const float* __restrict__ A1, long long a1_bs, int split,
               const float* __restrict__ Xin, const float* __restrict__ GFin,
               const float* __restrict__ MFin,
               const float* __restrict__ W, const float* __restrict__ bias,
               float* __restrict__ Out, long long out_bs,
               int rows_per_batch, int total_rows)
{
    constexpr int KP = (K + 4) & ~3;          // padded row stride, mult of 4 (16B align)
    __shared__ float As[64][KP];
    const int t = threadIdx.x;
    const int row0 = blockIdx.x * 64;

    // ---- stage A tile ----
    for (int e = t; e < 64 * K; e += 256) {
        int i = e / K;
        int k = e - i * K;
        int gr = row0 + i;
        float v = 0.0f;
        if (gr < total_rows) {
            int b = gr / rows_per_batch;
            int r = gr - b * rows_per_batch;
            if (MODE == 1) {
                if (k < FEAT) {
                    v = (r < NGRID) ? Xin[((long long)b * NGRID + r) * FEAT + k] : 0.0f;
                } else {
                    v = (r < NGRID) ? GFin[r * FI_ + (k - FEAT)]
                                    : MFin[(r - NGRID) * FI_ + (k - FEAT)];
                }
            } else {
                const float* srcp;
                if (A1 != nullptr && r >= split)
                    srcp = A1 + b * a1_bs + (long long)(r - split) * HD;
                else
                    srcp = A0 + b * a0_bs + (long long)r * HD;
                v = srcp[k];
            }
        }
        As[i][k] = v;
    }
    __syncthreads();

    const int cg = t & 31;          // 32 col groups of 4
    const int rg = t >> 5;          // 8 row groups of 8
    const int c0 = cg * 4;
    const int r0 = rg * 8;

    float acc[8][4];
#pragma unroll
    for (int i = 0; i < 8; ++i)
#pragma unroll
        for (int j = 0; j < 4; ++j) acc[i][j] = 0.0f;

    constexpr int KR4 = (K / 4) * 4;
#pragma unroll 2
    for (int k0 = 0; k0 < KR4; k0 += 4) {
        float4 wv[4];
        if (NOUT % 4 == 0) {
#pragma unroll
            for (int kk = 0; kk < 4; ++kk)
                wv[kk] = *(const float4*)&W[(k0 + kk) * NOUT + c0];
        } else {
#pragma unroll
            for (int kk = 0; kk < 4; ++kk) {
                const float* wr = W + (k0 + kk) * NOUT;
                wv[kk].x = (c0 + 0 < NOUT) ? wr[c0 + 0] : 0.0f;
                wv[kk].y = (c0 + 1 < NOUT) ? wr[c0 + 1] : 0.0f;
                wv[kk].z = (c0 + 2 < NOUT) ? wr[c0 + 2] : 0.0f;
                wv[kk].w = (c0 + 3 < NOUT) ? wr[c0 + 3] : 0.0f;
            }
        }
#pragma unroll
        for (int i = 0; i < 8; ++i) {
            float4 av = *(const float4*)&As[r0 + i][k0];
            acc[i][0] = fmaf(av.x, wv[0].x, acc[i][0]);
            acc[i][1] = fmaf(av.x, wv[0].y, acc[i][1]);
            acc[i][2] = fmaf(av.x, wv[0].z, acc[i][2]);
            acc[i][3] = fmaf(av.x, wv[0].w, acc[i][3]);
            acc[i][0] = fmaf(av.y, wv[1].x, acc[i][0]);
            acc[i][1] = fmaf(av.y, wv[1].y, acc[i][1]);
            acc[i][2] = fmaf(av.y, wv[1].z, acc[i][2]);
            acc[i][3] = fmaf(av.y, wv[1].w, acc[i][3]);
            acc[i][0] = fmaf(av.z, wv[2].x, acc[i][0]);
            acc[i][1] = fmaf(av.z, wv[2].y, acc[i][1]);
            acc[i][2] = fmaf(av.z, wv[2].z, acc[i][2]);
            acc[i][3] = fmaf(av.z, wv[2].w, acc[i][3]);
            acc[i][0] = fmaf(av.w, wv[3].x, acc[i][0]);
            acc[i][1] = fmaf(av.w, wv[3].y, acc[i][1]);
            acc[i][2] = fmaf(av.w, wv[3].z, acc[i][2]);
            acc[i][3] = fmaf(av.w, wv[3].w, acc[i][3]);
        }
    }
    // K tail (K=159 -> 3 extra)
    for (int k = KR4; k < K; ++k) {
        float w_[4];
#pragma unroll
        for (int j = 0; j < 4; ++j) {
            int c = c0 + j;
            w_[j] = (c < NOUT) ? W[k * NOUT + c] : 0.0f;
        }
#pragma unroll
        for (int i = 0; i < 8; ++i) {
            float a = As[r0 + i][k];
#pragma unroll
            for (int j = 0; j < 4; ++j) acc[i][j] = fmaf(a, w_[j], acc[i][j]);
        }
    }

    // ---- store ----
#pragma unroll
    for (int i = 0; i < 8; ++i) {
        int gr = row0 + r0 + i;
        if (gr >= total_rows) continue;
        int b = gr / rows_per_batch;
        int r = gr - b * rows_per_batch;
        float* orow = Out + b * out_bs + (long long)r * NOUT;
#pragma unroll
        for (int j = 0; j < 4; ++j) {
            int c = c0 + j;
            if (c < NOUT) {
                float v = acc[i][j];
                if (bias) v += bias[c];
                if (RELU) v = fmaxf(v, 0.0f);
                orow[c] = v;
            }
        }
    }
}

// ---------------------------------------------------------------------------
// Self-loop term (also zero-inits / bias-inits the aggregation buffer):
// out[b, r, c] = XW[b, r, c] * dinv[r]^2  (+ bias[c] if given)
// out has `rows` rows per batch; XW may have more (dec output slice case).
// ---------------------------------------------------------------------------
__global__ void selfloop_kernel(const float* __restrict__ XW, long long in_bs,
                                const float* __restrict__ dinv,
                                const float* __restrict__ bias,
                                float* __restrict__ out, long long out_bs,
                                int rows, int nc)
{
    long long idx = (long long)blockIdx.x * 256 + threadIdx.x;
    long long per_b = (long long)rows * nc;
    if (idx >= (long long)BB * per_b) return;
    int b = (int)(idx / per_b);
    long long rem = idx - (long long)b * per_b;
    int r = (int)(rem / nc);
    int c = (int)(rem - (long long)r * nc);
    float dv = dinv[r];
    float v = XW[b * in_bs + (long long)r * nc + c] * dv * dv;
    if (bias) v += bias[c];
    out[b * out_bs + rem] = v;
}

// ---------------------------------------------------------------------------
// Edge scatter: out[b, dst, c] += XW[b, src, c] * dinv[src] * dinv[dst]
// grid = (E, B), block = 128 (guard c < nc)
// ---------------------------------------------------------------------------
__global__ void scatter_kernel(const float* __restrict__ XW, long long in_bs,
                               const int* __restrict__ src, const int* __restrict__ dst,
                               const float* __restrict__ dinv,
                               float* __restrict__ out, long long out_bs, int nc)
{
    int c = threadIdx.x;
    if (c >= nc) return;
    int e = blockIdx.x;
    int b = blockIdx.y;
    int s = src[e];
    int d = dst[e];
    float norm = dinv[s] * dinv[d];
    float v = XW[b * in_bs + (long long)s * nc + c] * norm;
    atomicAdd(&out[b * out_bs + (long long)d * nc + c], v);
}

// ---------------------------------------------------------------------------
// Finalize: buf[i] = act(buf[i] + bias[i % nc])
// ---------------------------------------------------------------------------
__global__ void finalize_kernel(float* __restrict__ buf, const float* __restrict__ bias,
                                long long total, int nc, int relu)
{
    long long idx = (long long)blockIdx.x * 256 + threadIdx.x;
    if (idx >= total) return;
    int c = (int)(idx % nc);
    float v = buf[idx] + bias[c];
    if (relu) v = fmaxf(v, 0.0f);
    buf[idx] = v;
}

// ---------------------------------------------------------------------------
static inline int ceil_div(long long a, int b) { return (int)((a + b - 1) / b); }

extern "C" void kernel_launch(void* const* d_in, const int* in_sizes, int n_in,
                              void* d_out, int out_size, void* d_ws, size_t ws_size,
                              hipStream_t stream)
{
    const float* X    = (const float*)d_in[0];
    const float* GF   = (const float*)d_in[1];
    const float* MF   = (const float*)d_in[2];
    const float* emw1 = (const float*)d_in[3];
    const float* emb1 = (const float*)d_in[4];
    const float* emw2 = (const float*)d_in[5];
    const float* emb2 = (const float*)d_in[6];
    const float* egw1 = (const float*)d_in[7];
    const float* egb1 = (const float*)d_in[8];
    const float* egw2 = (const float*)d_in[9];
    const float* egb2 = (const float*)d_in[10];
    const float* pgw1 = (const float*)d_in[11];
    const float* pgb1 = (const float*)d_in[12];
    const float* pgw2 = (const float*)d_in[13];
    const float* pgb2 = (const float*)d_in[14];
    const float* dgw1 = (const float*)d_in[15];
    const float* dgb1 = (const float*)d_in[16];
    const float* dgw2 = (const float*)d_in[17];
    const float* dgb2 = (const float*)d_in[18];
    const int* enc_src = (const int*)d_in[19];
    const int* enc_dst = (const int*)d_in[20];
    const int* proc_src = (const int*)d_in[21];
    const int* proc_dst = (const int*)d_in[22];
    const int* dec_src = (const int*)d_in[23];
    const int* dec_dst = (const int*)d_in[24];
    float* out = (float*)d_out;

    // Workspace layout (floats). Total ~46.6M floats = ~187 MB.
    float* ws_f = (float*)d_ws;
    const long long BNH = (long long)BB * NTOT * HD;    // 19,302,912
    const long long BMH = (long long)BB * NMESH * HD;   //  2,621,952
    float* P  = ws_f;
    float* Q  = P  + BNH;
    float* mw = Q  + BNH;
    float* m1 = mw + BMH;
    float* m2 = m1 + BMH;
    float* dinv_enc  = m2 + BMH;          // [NTOT]
    float* dinv_proc = dinv_enc + NTOT;   // [NMESH]
    float* dinv_dec  = dinv_proc + NMESH; // [NTOT]

    const long long NH_BS = (long long)NTOT * HD;
    const long long MH_BS = (long long)NMESH * HD;

    // ---- degree -> dinv ----
    int totdeg = NTOT + NMESH + NTOT;
    fill1_kernel<<<ceil_div(totdeg, 256), 256, 0, stream>>>(dinv_enc, totdeg);
    count_edges_kernel<<<ceil_div(NE_ENC, 256), 256, 0, stream>>>(enc_dst, dinv_enc, NE_ENC);
    count_edges_kernel<<<ceil_div(NE_PROC, 256), 256, 0, stream>>>(proc_dst, dinv_proc, NE_PROC);
    count_edges_kernel<<<ceil_div(NE_DEC, 256), 256, 0, stream>>>(dec_dst, dinv_dec, NE_DEC);
    rsqrt_kernel<<<ceil_div(totdeg, 256), 256, 0, stream>>>(dinv_enc, totdeg);

    const int ROWS_N = BB * NTOT;    // 150804
    const int ROWS_M = BB * NMESH;   // 20484
    const int GB_N = ceil_div(ROWS_N, 64);   // GEMM blocks over all nodes
    const int GB_M = ceil_div(ROWS_M, 64);

    // ---- encoder MLP ----
    // h1 = relu(Xall @ emw1 + emb1) -> P     (Xall fused in loader)
    gemm_rows<KENC, HD, 1, 1><<<GB_N, 256, 0, stream>>>(
        nullptr, 0, nullptr, 0, 0, X, GF, MF, emw1, emb1, P, NH_BS, NTOT, ROWS_N);
    // h = h1 @ emw2 + emb2 -> P (in-place)
    gemm_rows<HD, HD, 0, 0><<<GB_N, 256, 0, stream>>>(
        P, NH_BS, nullptr, 0, 0, nullptr, nullptr, nullptr, emw2, emb2, P, NH_BS, NTOT, ROWS_N);

    const int EL_N  = ceil_div((long long)BB * NTOT * HD, 256);
    const int EL_M  = ceil_div((long long)BB * NMESH * HD, 256);

    // ---- encoder GCN conv 1 (relu) ----
    gemm_rows<HD, HD, 0, 0><<<GB_N, 256, 0, stream>>>(
        P, NH_BS, nullptr, 0, 0, nullptr, nullptr, nullptr, egw1, nullptr, Q, NH_BS, NTOT, ROWS_N);
    selfloop_kernel<<<EL_N, 256, 0, stream>>>(Q, NH_BS, dinv_enc, nullptr, P, NH_BS, NTOT, HD);
    scatter_kernel<<<dim3(NE_ENC, BB), 128, 0, stream>>>(Q, NH_BS, enc_src, enc_dst, dinv_enc, P, NH_BS, HD);
    finalize_kernel<<<EL_N, 256, 0, stream>>>(P, egb1, (long long)BB * NTOT * HD, HD, 1);

    // ---- encoder GCN conv 2 (no relu) -> h2 in P ----
    gemm_rows<HD, HD, 0, 0><<<GB_N, 256, 0, stream>>>(
        P, NH_BS, nullptr, 0, 0, nullptr, nullptr, nullptr, egw2, nullptr, Q, NH_BS, NTOT, ROWS_N);
    selfloop_kernel<<<EL_N, 256, 0, stream>>>(Q, NH_BS, dinv_enc, nullptr, P, NH_BS, NTOT, HD);
    scatter_kernel<<<dim3(NE_ENC, BB), 128, 0, stream>>>(Q, NH_BS, enc_src, enc_dst, dinv_enc, P, NH_BS, HD);
    finalize_kernel<<<EL_N, 256, 0, stream>>>(P, egb2, (long long)BB * NTOT * HD, HD, 0);

    // ---- processor GCN conv 1 on mesh part (relu) ----
    gemm_rows<HD, HD, 0, 0><<<GB_M, 256, 0, stream>>>(
        P + (long long)NGRID * HD, NH_BS, nullptr, 0, 0, nullptr, nullptr, nullptr,
        pgw1, nullptr, mw, MH_BS, NMESH, ROWS_M);
    selfloop_kernel<<<EL_M, 256, 0, stream>>>(mw, MH_BS, dinv_proc, nullptr, m1, MH_BS, NMESH, HD);
    scatter_kernel<<<dim3(NE_PROC, BB), 128, 0, stream>>>(mw, MH_BS, proc_src, proc_dst, dinv_proc, m1, MH_BS, HD);
    finalize_kernel<<<EL_M, 256, 0, stream>>>(m1, pgb1, (long long)BB * NMESH * HD, HD, 1);

    // ---- processor GCN conv 2 (no relu) -> m2 ----
    gemm_rows<HD, HD, 0, 0><<<GB_M, 256, 0, stream>>>(
        m1, MH_BS, nullptr, 0, 0, nullptr, nullptr, nullptr, pgw2, nullptr, mw, MH_BS, NMESH, ROWS_M);
    selfloop_kernel<<<EL_M, 256, 0, stream>>>(mw, MH_BS, dinv_proc, nullptr, m2, MH_BS, NMESH, HD);
    scatter_kernel<<<dim3(NE_PROC, BB), 128, 0, stream>>>(mw, MH_BS, proc_src, proc_dst, dinv_proc, m2, MH_BS, HD);
    finalize_kernel<<<EL_M, 256, 0, stream>>>(m2, pgb2, (long long)BB * NMESH * HD, HD, 0);

    // ---- decoder GCN conv 1 over pf = [grid_h (P rows <NGRID) | m2] (relu) ----
    gemm_rows<HD, HD, 0, 0><<<GB_N, 256, 0, stream>>>(
        P, NH_BS, m2, MH_BS, NGRID, nullptr, nullptr, nullptr, dgw1, nullptr, Q, NH_BS, NTOT, ROWS_N);
    selfloop_kernel<<<EL_N, 256, 0, stream>>>(Q, NH_BS, dinv_dec, nullptr, P, NH_BS, NTOT, HD);
    scatter_kernel<<<dim3(NE_DEC, BB), 128, 0, stream>>>(Q, NH_BS, dec_src, dec_dst, dinv_dec, P, NH_BS, HD);
    finalize_kernel<<<EL_N, 256, 0, stream>>>(P, dgb1, (long long)BB * NTOT * HD, HD, 1);

    // ---- decoder GCN conv 2 -> d_out (grid rows only) ----
    const long long NO_BS = (long long)NTOT * OUTD;
    const long long GO_BS = (long long)NGRID * OUTD;
    gemm_rows<HD, OUTD, 0, 0><<<GB_N, 256, 0, stream>>>(
        P, NH_BS, nullptr, 0, 0, nullptr, nullptr, nullptr, dgw2, nullptr, Q, NO_BS, NTOT, ROWS_N);
    // self-loop + bias for grid rows (full-coverage init of d_out)
    selfloop_kernel<<<ceil_div((long long)BB * NGRID * OUTD, 256), 256, 0, stream>>>(
        Q, NO_BS, dinv_dec, dgb2, out, GO_BS, NGRID, OUTD);
    scatter_kernel<<<dim3(NE_DEC, BB), 128, 0, stream>>>(Q, NO_BS, dec_src, dec_dst, dinv_dec, out, GO_BS, OUTD);
}

// Round 4
// 1503.816 us; speedup vs baseline: 1.3355x; 1.3355x over previous
//
#include <hip/hip_runtime.h>
#include <hip/hip_bf16.h>

// Problem constants (from reference)
#define NGRID  65160
#define NMESH  10242
#define NTOT   75402      // NGRID + NMESH
#define FEAT   156
#define FI_    3
#define KENC   159        // FEAT + FI_
#define HD     128
#define OUTD   78
#define BB     2
#define NE_ENC 130320
#define NE_PROC 81920
#define NE_DEC 195480

typedef __attribute__((ext_vector_type(8))) short bf16x8;
typedef __attribute__((ext_vector_type(4))) float f32x4;

__device__ __forceinline__ short bf16_rtn(float v) {
    unsigned u = __builtin_bit_cast(unsigned, v);
    u += 0x7FFFu + ((u >> 16) & 1u);
    return (short)(u >> 16);
}
__device__ __forceinline__ float bf16_f32(short s) {
    unsigned u = ((unsigned)(unsigned short)s) << 16;
    return __builtin_bit_cast(float, u);
}

// ---------------------------------------------------------------------------
// Weight prep: W[K][N] f32 -> WT_hi/WT_lo [NP][KP] bf16 (transposed, split,
// zero-padded). Split: w = hi + lo with hi = bf16(w), lo = bf16(w - hi).
// ---------------------------------------------------------------------------
__global__ void wprep_kernel(const float* __restrict__ W, int K, int Nc,
                             short* __restrict__ WTh, short* __restrict__ WTl,
                             int KP, int NP)
{
    int idx = blockIdx.x * 256 + threadIdx.x;
    if (idx >= KP * NP) return;
    int c = idx / KP;
    int k = idx - c * KP;
    float v = (k < K && c < Nc) ? W[k * Nc + c] : 0.0f;
    short h = bf16_rtn(v);
    WTh[idx] = h;
    WTl[idx] = bf16_rtn(v - bf16_f32(h));
}

// ---------------------------------------------------------------------------
// Degree / normalization kernels
// ---------------------------------------------------------------------------
__global__ void fill1_kernel(float* __restrict__ p, int n) {
    int i = blockIdx.x * 256 + threadIdx.x;
    if (i < n) p[i] = 1.0f;   // self-loop contributes 1 to every node's degree
}

__global__ void count_edges_kernel(const int* __restrict__ dst, float* __restrict__ deg, int ne) {
    int e = blockIdx.x * 256 + threadIdx.x;
    if (e < ne) atomicAdd(&deg[dst[e]], 1.0f);
}

__global__ void rsqrt_kernel(float* __restrict__ p, int n) {
    int i = blockIdx.x * 256 + threadIdx.x;
    if (i < n) p[i] = rsqrtf(p[i]);
}

// ---------------------------------------------------------------------------
// MFMA GEMM (split-bf16, ~f32 precision): Out = A @ W (+ fused epilogues)
// Block: 256 thr = 4 waves; 64 rows/block, wave w owns rows [w*16, w*16+16).
// Each wave computes 16 x NOUT via NCT 16x16 col-tiles, K in steps of 32.
// mfma_f32_16x16x32_bf16 fragment mapping:
//   A: lane l holds A[l%16][k0 + 8*(l/16) + j], j=0..7
//   B: lane l holds B[k0 + 8*(l/16) + j][l%16]  (read from WT[N][K], contiguous)
//   D: lane l, reg i -> row (l/16)*4+i, col l%16   [verified layout, learn_hip m89]
// MODE 0: A rows from A0 (stride KP floats)
// MODE 1: fused encoder concat [X | GF] / [0 | MF]  (K=159, KP=160)
// MODE 2: A from A0 (r < split) else A1 (dec concat)
// EPI 0: Q = acc + bias (opt relu)          [MLP layers]
// EPI 1: Q = acc; P = acc*dinv[r]^2 + bias for r < p_rows   [GCN layers]
// RELU_IN: relu applied to A elements on load (deferred relu of prev layer).
// In-place A==Q is safe: each block reads only the 64 rows it writes, and all
// loads precede all stores within each wave.
// ---------------------------------------------------------------------------
template<int KP, int NOUT, int MODE, int RELU_IN, int EPI, int RELU_OUT>
__global__ __launch_bounds__(256)
void gemm_mfma(const float* __restrict__ A0, long long a0_bs,
               const float* __restrict__ A1, long long a1_bs, int split,
               const float* __restrict__ Xin, const float* __restrict__ GFin,
               const float* __restrict__ MFin,
               const short* __restrict__ WTh, const short* __restrict__ WTl,
               const float* __restrict__ bias, const float* __restrict__ dinv,
               float* __restrict__ Qout, long long q_bs,
               float* __restrict__ Pout, long long p_bs, int p_rows,
               int rows_per_batch, int total_rows)
{
    constexpr int NCT = (NOUT + 15) / 16;
    const int t = threadIdx.x;
    const int w = t >> 6;
    const int l = t & 63;
    const int lane15 = l & 15;
    const int g = l >> 4;

    // Resolve this lane's A row once (fixed across the K loop)
    const int gr_a = blockIdx.x * 64 + w * 16 + lane15;
    const bool a_valid = (gr_a < total_rows);
    int b_a = 0, r_a = 0;
    const float* arow = nullptr;
    if (a_valid) {
        b_a = gr_a / rows_per_batch;
        r_a = gr_a - b_a * rows_per_batch;
        if (MODE == 0) {
            arow = A0 + b_a * a0_bs + (long long)r_a * KP;
        } else if (MODE == 2) {
            if (r_a >= split) arow = A1 + b_a * a1_bs + (long long)(r_a - split) * KP;
            else              arow = A0 + b_a * a0_bs + (long long)r_a * KP;
        }
    }

    f32x4 acc[NCT];
#pragma unroll
    for (int ct = 0; ct < NCT; ++ct) acc[ct] = (f32x4){0.f, 0.f, 0.f, 0.f};

#pragma unroll
    for (int k0 = 0; k0 < KP; k0 += 32) {
        const int kbase = k0 + g * 8;
        float av[8];
        if (MODE == 1) {
#pragma unroll
            for (int j = 0; j < 8; ++j) av[j] = 0.0f;
            if (a_valid) {
                const bool gridr = (r_a < NGRID);
                if (gridr && kbase + 8 <= FEAT) {
                    const float* xrow = Xin + ((long long)b_a * NGRID + r_a) * FEAT + kbase;
#pragma unroll
                    for (int j2 = 0; j2 < 4; ++j2) {   // rows are 8B-aligned (156 floats)
                        float2 v = *(const float2*)(xrow + j2 * 2);
                        av[j2 * 2]     = v.x;
                        av[j2 * 2 + 1] = v.y;
                    }
                } else {
#pragma unroll
                    for (int j = 0; j < 8; ++j) {
                        int k = kbase + j;
                        float v = 0.0f;
                        if (k < FEAT) {
                            if (gridr) v = Xin[((long long)b_a * NGRID + r_a) * FEAT + k];
                        } else if (k < KENC) {
                            v = gridr ? GFin[r_a * FI_ + (k - FEAT)]
                                      : MFin[(r_a - NGRID) * FI_ + (k - FEAT)];
                        }
                        av[j] = v;
                    }
                }
            }
        } else {
            if (a_valid) {
                float4 v0 = *(const float4*)(arow + kbase);
                float4 v1 = *(const float4*)(arow + kbase + 4);
                av[0] = v0.x; av[1] = v0.y; av[2] = v0.z; av[3] = v0.w;
                av[4] = v1.x; av[5] = v1.y; av[6] = v1.z; av[7] = v1.w;
            } else {
#pragma unroll
                for (int j = 0; j < 8; ++j) av[j] = 0.0f;
            }
        }

        // split f32 -> hi/lo bf16 in-register
        bf16x8 ah, al;
#pragma unroll
        for (int j = 0; j < 8; ++j) {
            float v = av[j];
            if (RELU_IN) v = fmaxf(v, 0.0f);
            short h = bf16_rtn(v);
            ah[j] = h;
            al[j] = bf16_rtn(v - bf16_f32(h));
        }

#pragma unroll
        for (int ct = 0; ct < NCT; ++ct) {
            const long long boff = (long long)(ct * 16 + lane15) * KP + kbase;
            bf16x8 bh = *(const bf16x8*)(WTh + boff);
            bf16x8 bl = *(const bf16x8*)(WTl + boff);
            acc[ct] = __builtin_amdgcn_mfma_f32_16x16x32_bf16(ah, bh, acc[ct], 0, 0, 0);
            acc[ct] = __builtin_amdgcn_mfma_f32_16x16x32_bf16(al, bh, acc[ct], 0, 0, 0);
            acc[ct] = __builtin_amdgcn_mfma_f32_16x16x32_bf16(ah, bl, acc[ct], 0, 0, 0);
        }
    }

    // ---- epilogue ----
#pragma unroll
    for (int i = 0; i < 4; ++i) {
        const int gr = blockIdx.x * 64 + w * 16 + g * 4 + i;
        if (gr >= total_rows) continue;
        const int b = gr / rows_per_batch;
        const int r = gr - b * rows_per_batch;
        float* qrow = Qout + b * q_bs + (long long)r * NOUT;
        float dv2 = 0.0f;
        const bool do_p = (EPI == 1) && (r < p_rows);
        if (do_p) { float dvv = dinv[r]; dv2 = dvv * dvv; }
        float* prow = (EPI == 1) ? (Pout + b * p_bs + (long long)r * NOUT) : nullptr;
#pragma unroll
        for (int ct = 0; ct < NCT; ++ct) {
            const int c = ct * 16 + lane15;
            if ((NOUT % 16 != 0) && c >= NOUT) continue;
            float v = acc[ct][i];
            if (EPI == 0) {
                v += bias[c];
                if (RELU_OUT) v = fmaxf(v, 0.0f);
                qrow[c] = v;
            } else {
                qrow[c] = v;
                if (do_p) prow[c] = v * dv2 + bias[c];
            }
        }
    }
}

// ---------------------------------------------------------------------------
// Edge scatter: out[b, dst, c] += XW[b, src, c] * dinv[src] * dinv[dst]
// ---------------------------------------------------------------------------
__global__ void scatter_kernel(const float* __restrict__ XW, long long in_bs,
                               const int* __restrict__ src, const int* __restrict__ dst,
                               const float* __restrict__ dinv,
                               float* __restrict__ out, long long out_bs, int nc)
{
    int c = threadIdx.x;
    if (c >= nc) return;
    int e = blockIdx.x;
    int b = blockIdx.y;
    int s = src[e];
    int d = dst[e];
    float norm = dinv[s] * dinv[d];
    float v = XW[b * in_bs + (long long)s * nc + c] * norm;
    atomicAdd(&out[b * out_bs + (long long)d * nc + c], v);
}

// ---------------------------------------------------------------------------
static inline int ceil_div(long long a, int b) { return (int)((a + b - 1) / b); }

extern "C" void kernel_launch(void* const* d_in, const int* in_sizes, int n_in,
                              void* d_out, int out_size, void* d_ws, size_t ws_size,
                              hipStream_t stream)
{
    const float* X    = (const float*)d_in[0];
    const float* GF   = (const float*)d_in[1];
    const float* MF   = (const float*)d_in[2];
    const float* emw1 = (const float*)d_in[3];
    const float* emb1 = (const float*)d_in[4];
    const float* emw2 = (const float*)d_in[5];
    const float* emb2 = (const float*)d_in[6];
    const float* egw1 = (const float*)d_in[7];
    const float* egb1 = (const float*)d_in[8];
    const float* egw2 = (const float*)d_in[9];
    const float* egb2 = (const float*)d_in[10];
    const float* pgw1 = (const float*)d_in[11];
    const float* pgb1 = (const float*)d_in[12];
    const float* pgw2 = (const float*)d_in[13];
    const float* pgb2 = (const float*)d_in[14];
    const float* dgw1 = (const float*)d_in[15];
    const float* dgb1 = (const float*)d_in[16];
    const float* dgw2 = (const float*)d_in[17];
    const float* dgb2 = (const float*)d_in[18];
    const int* enc_src = (const int*)d_in[19];
    const int* enc_dst = (const int*)d_in[20];
    const int* proc_src = (const int*)d_in[21];
    const int* proc_dst = (const int*)d_in[22];
    const int* dec_src = (const int*)d_in[23];
    const int* dec_dst = (const int*)d_in[24];
    float* out = (float*)d_out;

    // ---- workspace layout ----
    float* ws_f = (float*)d_ws;
    const long long BNH = (long long)BB * NTOT * HD;    // 19,302,912 floats
    const long long BMH = (long long)BB * NMESH * HD;   //  2,621,952 floats
    float* Abuf = ws_f;
    float* Bbuf = Abuf + BNH;
    float* m1   = Bbuf + BNH;
    float* m2   = m1 + BMH;
    float* dinv_enc  = m2 + BMH;            // [NTOT]
    float* dinv_proc = dinv_enc + NTOT;     // [NMESH]
    float* dinv_dec  = dinv_proc + NMESH;   // [NTOT]
    long long fcnt = 2 * BNH + 2 * BMH + (long long)(NTOT + NMESH + NTOT);
    fcnt = (fcnt + 3) & ~3LL;               // 16B align for bf16 tail
    short* wt = (short*)(ws_f + fcnt);

    // WT (transposed, split) storage: [NP][KP] bf16 each for hi and lo
    const int KP1 = 160, NP1 = 128;         // emw1: K=159 -> pad 160
    const int KPH = 128, NPH = 128;         // 128x128 weights
    const int NPO = 80;                     // dgw2: NOUT=78 -> pad 80
    short* wt_emw1_h = wt;                      short* wt_emw1_l = wt_emw1_h + NP1 * KP1;
    short* wt_emw2_h = wt_emw1_l + NP1 * KP1;   short* wt_emw2_l = wt_emw2_h + NPH * KPH;
    short* wt_egw1_h = wt_emw2_l + NPH * KPH;   short* wt_egw1_l = wt_egw1_h + NPH * KPH;
    short* wt_egw2_h = wt_egw1_l + NPH * KPH;   short* wt_egw2_l = wt_egw2_h + NPH * KPH;
    short* wt_pgw1_h = wt_egw2_l + NPH * KPH;   short* wt_pgw1_l = wt_pgw1_h + NPH * KPH;
    short* wt_pgw2_h = wt_pgw1_l + NPH * KPH;   short* wt_pgw2_l = wt_pgw2_h + NPH * KPH;
    short* wt_dgw1_h = wt_pgw2_l + NPH * KPH;   short* wt_dgw1_l = wt_dgw1_h + NPH * KPH;
    short* wt_dgw2_h = wt_dgw1_l + NPH * KPH;   short* wt_dgw2_l = wt_dgw2_h + NPO * KPH;

    // ---- weight prep ----
    wprep_kernel<<<ceil_div(NP1 * KP1, 256), 256, 0, stream>>>(emw1, KENC, HD, wt_emw1_h, wt_emw1_l, KP1, NP1);
    wprep_kernel<<<ceil_div(NPH * KPH, 256), 256, 0, stream>>>(emw2, HD, HD, wt_emw2_h, wt_emw2_l, KPH, NPH);
    wprep_kernel<<<ceil_div(NPH * KPH, 256), 256, 0, stream>>>(egw1, HD, HD, wt_egw1_h, wt_egw1_l, KPH, NPH);
    wprep_kernel<<<ceil_div(NPH * KPH, 256), 256, 0, stream>>>(egw2, HD, HD, wt_egw2_h, wt_egw2_l, KPH, NPH);
    wprep_kernel<<<ceil_div(NPH * KPH, 256), 256, 0, stream>>>(pgw1, HD, HD, wt_pgw1_h, wt_pgw1_l, KPH, NPH);
    wprep_kernel<<<ceil_div(NPH * KPH, 256), 256, 0, stream>>>(pgw2, HD, HD, wt_pgw2_h, wt_pgw2_l, KPH, NPH);
    wprep_kernel<<<ceil_div(NPH * KPH, 256), 256, 0, stream>>>(dgw1, HD, HD, wt_dgw1_h, wt_dgw1_l, KPH, NPH);
    wprep_kernel<<<ceil_div(NPO * KPH, 256), 256, 0, stream>>>(dgw2, HD, OUTD, wt_dgw2_h, wt_dgw2_l, KPH, NPO);

    // ---- degrees -> dinv ----
    const int totdeg = NTOT + NMESH + NTOT;
    fill1_kernel<<<ceil_div(totdeg, 256), 256, 0, stream>>>(dinv_enc, totdeg);
    count_edges_kernel<<<ceil_div(NE_ENC, 256), 256, 0, stream>>>(enc_dst, dinv_enc, NE_ENC);
    count_edges_kernel<<<ceil_div(NE_PROC, 256), 256, 0, stream>>>(proc_dst, dinv_proc, NE_PROC);
    count_edges_kernel<<<ceil_div(NE_DEC, 256), 256, 0, stream>>>(dec_dst, dinv_dec, NE_DEC);
    rsqrt_kernel<<<ceil_div(totdeg, 256), 256, 0, stream>>>(dinv_enc, totdeg);

    const int ROWS_N = BB * NTOT;                 // 150804
    const int ROWS_M = BB * NMESH;                // 20484
    const int GB_N = ceil_div(ROWS_N, 64);
    const int GB_M = ceil_div(ROWS_M, 64);
    const long long NH_BS = (long long)NTOT * HD;
    const long long MH_BS = (long long)NMESH * HD;

    // ---- encoder MLP ----
    // A = relu(Xall @ emw1 + emb1)
    gemm_mfma<160, HD, 1, 0, 0, 1><<<GB_N, 256, 0, stream>>>(
        nullptr, 0, nullptr, 0, 0, X, GF, MF, wt_emw1_h, wt_emw1_l,
        emb1, nullptr, Abuf, NH_BS, nullptr, 0, 0, NTOT, ROWS_N);
    // A = A @ emw2 + emb2  (in-place)
    gemm_mfma<HD, HD, 0, 0, 0, 0><<<GB_N, 256, 0, stream>>>(
        Abuf, NH_BS, nullptr, 0, 0, nullptr, nullptr, nullptr, wt_emw2_h, wt_emw2_l,
        emb2, nullptr, Abuf, NH_BS, nullptr, 0, 0, NTOT, ROWS_N);

    // ---- encoder GCN conv 1 (relu deferred to next A-load) ----
    gemm_mfma<HD, HD, 0, 0, 1, 0><<<GB_N, 256, 0, stream>>>(
        Abuf, NH_BS, nullptr, 0, 0, nullptr, nullptr, nullptr, wt_egw1_h, wt_egw1_l,
        egb1, dinv_enc, Abuf, NH_BS, Bbuf, NH_BS, NTOT, NTOT, ROWS_N);
    scatter_kernel<<<dim3(NE_ENC, BB), 128, 0, stream>>>(Abuf, NH_BS, enc_src, enc_dst, dinv_enc, Bbuf, NH_BS, HD);

    // ---- encoder GCN conv 2 (relu-in; no relu on output) -> h2 in Abuf ----
    gemm_mfma<HD, HD, 0, 1, 1, 0><<<GB_N, 256, 0, stream>>>(
        Bbuf, NH_BS, nullptr, 0, 0, nullptr, nullptr, nullptr, wt_egw2_h, wt_egw2_l,
        egb2, dinv_enc, Bbuf, NH_BS, Abuf, NH_BS, NTOT, NTOT, ROWS_N);
    scatter_kernel<<<dim3(NE_ENC, BB), 128, 0, stream>>>(Bbuf, NH_BS, enc_src, enc_dst, dinv_enc, Abuf, NH_BS, HD);

    // ---- processor GCN conv 1 on mesh rows of h2 (in-place XW into A-mesh) ----
    gemm_mfma<HD, HD, 0, 0, 1, 0><<<GB_M, 256, 0, stream>>>(
        Abuf + (long long)NGRID * HD, NH_BS, nullptr, 0, 0, nullptr, nullptr, nullptr,
        wt_pgw1_h, wt_pgw1_l, pgb1, dinv_proc,
        Abuf + (long long)NGRID * HD, NH_BS, m1, MH_BS, NMESH, NMESH, ROWS_M);
    scatter_kernel<<<dim3(NE_PROC, BB), 128, 0, stream>>>(Abuf + (long long)NGRID * HD, NH_BS,
                                                          proc_src, proc_dst, dinv_proc, m1, MH_BS, HD);

    // ---- processor GCN conv 2 (relu-in) -> m2 ----
    gemm_mfma<HD, HD, 0, 1, 1, 0><<<GB_M, 256, 0, stream>>>(
        m1, MH_BS, nullptr, 0, 0, nullptr, nullptr, nullptr, wt_pgw2_h, wt_pgw2_l,
        pgb2, dinv_proc, m1, MH_BS, m2, MH_BS, NMESH, NMESH, ROWS_M);
    scatter_kernel<<<dim3(NE_PROC, BB), 128, 0, stream>>>(m1, MH_BS, proc_src, proc_dst, dinv_proc, m2, MH_BS, HD);

    // ---- decoder GCN conv 1 over pf = [grid rows of Abuf | m2] ----
    gemm_mfma<HD, HD, 2, 0, 1, 0><<<GB_N, 256, 0, stream>>>(
        Abuf, NH_BS, m2, MH_BS, NGRID, nullptr, nullptr, nullptr, wt_dgw1_h, wt_dgw1_l,
        dgb1, dinv_dec, Bbuf, NH_BS, Abuf, NH_BS, NTOT, NTOT, ROWS_N);
    scatter_kernel<<<dim3(NE_DEC, BB), 128, 0, stream>>>(Bbuf, NH_BS, dec_src, dec_dst, dinv_dec, Abuf, NH_BS, HD);

    // ---- decoder GCN conv 2 (relu-in) -> d_out (grid rows) ----
    const long long NO_BS = (long long)NTOT * OUTD;
    const long long GO_BS = (long long)NGRID * OUTD;
    gemm_mfma<HD, OUTD, 0, 1, 1, 0><<<GB_N, 256, 0, stream>>>(
        Abuf, NH_BS, nullptr, 0, 0, nullptr, nullptr, nullptr, wt_dgw2_h, wt_dgw2_l,
        dgb2, dinv_dec, Bbuf, NO_BS, out, GO_BS, NGRID, NTOT, ROWS_N);
    scatter_kernel<<<dim3(NE_DEC, BB), 128, 0, stream>>>(Bbuf, NO_BS, dec_src, dec_dst, dinv_dec, out, GO_BS, OUTD);
}

// Round 7
// 1400.036 us; speedup vs baseline: 1.4345x; 1.0741x over previous
//
#include <hip/hip_runtime.h>
#include <hip/hip_bf16.h>

// Problem constants (from reference)
#define NGRID  65160
#define NMESH  10242
#define NTOT   75402      // NGRID + NMESH
#define FEAT   156
#define FI_    3
#define KENC   159        // FEAT + FI_
#define HD     128
#define OUTD   78
#define BB     2
#define NE_ENC 130320
#define NE_PROC 81920
#define NE_DEC 195480

typedef __attribute__((ext_vector_type(8))) short bf16x8;
typedef __attribute__((ext_vector_type(4))) float f32x4;

__device__ __forceinline__ short bf16_rtn(float v) {
    unsigned u = __builtin_bit_cast(unsigned, v);
    u += 0x7FFFu + ((u >> 16) & 1u);
    return (short)(u >> 16);
}
__device__ __forceinline__ float bf16_f32(short s) {
    unsigned u = ((unsigned)(unsigned short)s) << 16;
    return __builtin_bit_cast(float, u);
}

// ---------------------------------------------------------------------------
// Weight prep: W[K][N] f32 -> WT_hi/WT_lo [NP][KP] bf16 (transposed, split,
// zero-padded). Split: w = hi + lo with hi = bf16(w), lo = bf16(w - hi).
// ---------------------------------------------------------------------------
__global__ void wprep_kernel(const float* __restrict__ W, int K, int Nc,
                             short* __restrict__ WTh, short* __restrict__ WTl,
                             int KP, int NP)
{
    int idx = blockIdx.x * 256 + threadIdx.x;
    if (idx >= KP * NP) return;
    int c = idx / KP;
    int k = idx - c * KP;
    float v = (k < K && c < Nc) ? W[k * Nc + c] : 0.0f;
    short h = bf16_rtn(v);
    WTh[idx] = h;
    WTl[idx] = bf16_rtn(v - bf16_f32(h));
}

__global__ void zero_kernel(int* __restrict__ p, int n) {
    int i = blockIdx.x * 256 + threadIdx.x;
    if (i < n) p[i] = 0;
}

// ---------------------------------------------------------------------------
// CSR build: count (int atomics) -> exclusive scan (single WG) -> fill.
// dinv[i] = rsqrt(1 + in_degree[i])  (self-loop contributes 1).
// ---------------------------------------------------------------------------
__global__ void count_kernel(const int* __restrict__ dst, int* __restrict__ cnt, int ne) {
    int e = blockIdx.x * 256 + threadIdx.x;
    if (e < ne) atomicAdd(&cnt[dst[e]], 1);
}

__global__ __launch_bounds__(1024)
void scan_kernel(const int* __restrict__ in, int* __restrict__ out, int n) {
    __shared__ int buf[1024];
    __shared__ int carry_s;
    const int t = threadIdx.x;
    if (t == 0) carry_s = 0;
    __syncthreads();
    for (int base = 0; base < n; base += 1024) {
        const int i = base + t;
        const int v = (i < n) ? in[i] : 0;
        buf[t] = v;
        __syncthreads();
        for (int off = 1; off < 1024; off <<= 1) {
            int x = (t >= off) ? buf[t - off] : 0;
            __syncthreads();
            buf[t] += x;
            __syncthreads();
        }
        const int incl = buf[t];
        const int carry = carry_s;
        if (i < n) out[i] = carry + incl - v;   // exclusive
        __syncthreads();
        if (t == 1023) carry_s = carry + incl;
        __syncthreads();
    }
}

__global__ void dinv_kernel(const int* __restrict__ cnt, float* __restrict__ dinv, int n) {
    int i = blockIdx.x * 256 + threadIdx.x;
    if (i < n) dinv[i] = rsqrtf(1.0f + (float)cnt[i]);
}

__global__ void fillcsr_kernel(const int* __restrict__ src, const int* __restrict__ dst,
                               const int* __restrict__ rowptr, int* __restrict__ fill,
                               int* __restrict__ colsrc, int ne) {
    int e = blockIdx.x * 256 + threadIdx.x;
    if (e < ne) {
        int d = dst[e];
        int pos = atomicAdd(&fill[d], 1);
        colsrc[rowptr[d] + pos] = src[e];
    }
}

// ---------------------------------------------------------------------------
// MFMA GEMM (split-bf16, ~f32 precision): Q = A @ W (+ bias, + relu)
// Block: 256 thr = 4 waves; 64 rows/block, wave w owns rows [w*16, w*16+16).
// Each wave computes 16 x NOUT via NCT 16x16 col-tiles, K in steps of 32.
// mfma_f32_16x16x32_bf16 fragment mapping:
//   A: lane l holds A[l%16][k0 + 8*(l/16) + j], j=0..7
//   B: lane l holds B[k0 + 8*(l/16) + j][l%16]  (read from WT[N][K], contiguous)
//   D: lane l, reg i -> row (l/16)*4+i, col l%16   [verified layout, learn_hip m89]
// MODE 0: A rows from A0 (stride KP floats)
// MODE 1: fused encoder concat [X | GF] / [0 | MF]  (K=159, KP=160)
// MODE 2: A from A0 (r < split) else A1 (dec concat)
// In-place A==Q is safe: each block reads only the 64 rows it writes, and all
// loads precede all stores within each wave.
// ---------------------------------------------------------------------------
template<int KP, int NOUT, int MODE, int RELU_OUT>
__global__ __launch_bounds__(256)
void gemm_mfma(const float* __restrict__ A0, long long a0_bs,
               const float* __restrict__ A1, long long a1_bs, int split,
               const float* __restrict__ Xin, const float* __restrict__ GFin,
               const float* __restrict__ MFin,
               const short* __restrict__ WTh, const short* __restrict__ WTl,
               const float* __restrict__ bias,
               float* __restrict__ Qout, long long q_bs,
               int rows_per_batch, int total_rows)
{
    constexpr int NCT = (NOUT + 15) / 16;
    const int t = threadIdx.x;
    const int w = t >> 6;
    const int l = t & 63;
    const int lane15 = l & 15;
    const int g = l >> 4;

    // Resolve this lane's A row once (fixed across the K loop)
    const int gr_a = blockIdx.x * 64 + w * 16 + lane15;
    const bool a_valid = (gr_a < total_rows);
    int b_a = 0, r_a = 0;
    const float* arow = nullptr;
    if (a_valid) {
        b_a = gr_a / rows_per_batch;
        r_a = gr_a - b_a * rows_per_batch;
        if (MODE == 0) {
            arow = A0 + b_a * a0_bs + (long long)r_a * KP;
        } else if (MODE == 2) {
            if (r_a >= split) arow = A1 + b_a * a1_bs + (long long)(r_a - split) * KP;
            else              arow = A0 + b_a * a0_bs + (long long)r_a * KP;
        }
    }

    f32x4 acc[NCT];
#pragma unroll
    for (int ct = 0; ct < NCT; ++ct) acc[ct] = (f32x4){0.f, 0.f, 0.f, 0.f};

#pragma unroll
    for (int k0 = 0; k0 < KP; k0 += 32) {
        const int kbase = k0 + g * 8;
        float av[8];
        if (MODE == 1) {
#pragma unroll
            for (int j = 0; j < 8; ++j) av[j] = 0.0f;
            if (a_valid) {
                const bool gridr = (r_a < NGRID);
                if (gridr && kbase + 8 <= FEAT) {
                    const float* xrow = Xin + ((long long)b_a * NGRID + r_a) * FEAT + kbase;
#pragma unroll
                    for (int j2 = 0; j2 < 4; ++j2) {   // rows are 8B-aligned (156 floats)
                        float2 v = *(const float2*)(xrow + j2 * 2);
                        av[j2 * 2]     = v.x;
                        av[j2 * 2 + 1] = v.y;
                    }
                } else {
#pragma unroll
                    for (int j = 0; j < 8; ++j) {
                        int k = kbase + j;
                        float v = 0.0f;
                        if (k < FEAT) {
                            if (gridr) v = Xin[((long long)b_a * NGRID + r_a) * FEAT + k];
                        } else if (k < KENC) {
                            v = gridr ? GFin[r_a * FI_ + (k - FEAT)]
                                      : MFin[(r_a - NGRID) * FI_ + (k - FEAT)];
                        }
                        av[j] = v;
                    }
                }
            }
        } else {
            if (a_valid) {
                float4 v0 = *(const float4*)(arow + kbase);
                float4 v1 = *(const float4*)(arow + kbase + 4);
                av[0] = v0.x; av[1] = v0.y; av[2] = v0.z; av[3] = v0.w;
                av[4] = v1.x; av[5] = v1.y; av[6] = v1.z; av[7] = v1.w;
            } else {
#pragma unroll
                for (int j = 0; j < 8; ++j) av[j] = 0.0f;
            }
        }

        // split f32 -> hi/lo bf16 in-register
        bf16x8 ah, al;
#pragma unroll
        for (int j = 0; j < 8; ++j) {
            float v = av[j];
            short h = bf16_rtn(v);
            ah[j] = h;
            al[j] = bf16_rtn(v - bf16_f32(h));
        }

#pragma unroll
        for (int ct = 0; ct < NCT; ++ct) {
            const long long boff = (long long)(ct * 16 + lane15) * KP + kbase;
            bf16x8 bh = *(const bf16x8*)(WTh + boff);
            bf16x8 bl = *(const bf16x8*)(WTl + boff);
            acc[ct] = __builtin_amdgcn_mfma_f32_16x16x32_bf16(ah, bh, acc[ct], 0, 0, 0);
            acc[ct] = __builtin_amdgcn_mfma_f32_16x16x32_bf16(al, bh, acc[ct], 0, 0, 0);
            acc[ct] = __builtin_amdgcn_mfma_f32_16x16x32_bf16(ah, bl, acc[ct], 0, 0, 0);
        }
    }

    // ---- epilogue: Q = acc (+bias) (+relu) ----
#pragma unroll
    for (int i = 0; i < 4; ++i) {
        const int gr = blockIdx.x * 64 + w * 16 + g * 4 + i;
        if (gr >= total_rows) continue;
        const int b = gr / rows_per_batch;
        const int r = gr - b * rows_per_batch;
        float* qrow = Qout + b * q_bs + (long long)r * NOUT;
#pragma unroll
        for (int ct = 0; ct < NCT; ++ct) {
            const int c = ct * 16 + lane15;
            if ((NOUT % 16 != 0) && c >= NOUT) continue;
            float v = acc[ct][i];
            if (bias) v += bias[c];
            if (RELU_OUT) v = fmaxf(v, 0.0f);
            qrow[c] = v;
        }
    }
}

// ---------------------------------------------------------------------------
// CSR gather aggregation (no atomics):
//   Out[b,d,:] = act( Q[b,d,:]*dinv[d]^2 + sum_e Q[b,src[e],:]*dinv[src]*dinv[d]
//                     + bias )
// One 64-lane wave per (node, batch); block = 4 waves.
// NC=128: float2 per lane (coalesced 512B per row read/write).
// NC=78:  lane covers cols {lane, lane+64 (guarded)}.
// ---------------------------------------------------------------------------
template<int NC, int RELU>
__global__ __launch_bounds__(256)
void gather_kernel(const float* __restrict__ Q, long long q_bs,
                   const float* __restrict__ dinv,
                   const int* __restrict__ cnt, const int* __restrict__ rowptr,
                   const int* __restrict__ colsrc,
                   const float* __restrict__ bias,
                   float* __restrict__ Out, long long out_bs, int out_rows)
{
    const int wv = blockIdx.x * 4 + (threadIdx.x >> 6);
    const int lane = threadIdx.x & 63;
    if (wv >= out_rows * BB) return;
    const int b = wv / out_rows;
    const int d = wv - b * out_rows;
    const float dv = dinv[d];
    const float dv2 = dv * dv;
    const int beg = rowptr[d];
    const int num = cnt[d];
    const float* Qb = Q + b * q_bs;

    if (NC == 128) {
        const int c = lane * 2;
        float2 acc = *(const float2*)(Qb + (long long)d * NC + c);
        acc.x *= dv2; acc.y *= dv2;
        for (int e = 0; e < num; ++e) {
            int s = colsrc[beg + e];
            float ns = dinv[s] * dv;
            float2 v = *(const float2*)(Qb + (long long)s * NC + c);
            acc.x += v.x * ns;
            acc.y += v.y * ns;
        }
        acc.x += bias[c]; acc.y += bias[c + 1];
        if (RELU) { acc.x = fmaxf(acc.x, 0.f); acc.y = fmaxf(acc.y, 0.f); }
        *(float2*)(Out + b * out_bs + (long long)d * NC + c) = acc;
    } else {
        const int c1 = lane, c2 = lane + 64;
        const float* qd = Qb + (long long)d * NC;
        float a1 = qd[c1] * dv2;
        float a2 = (c2 < NC) ? qd[c2] * dv2 : 0.f;
        for (int e = 0; e < num; ++e) {
            int s = colsrc[beg + e];
            float ns = dinv[s] * dv;
            const float* qs = Qb + (long long)s * NC;
            a1 += qs[c1] * ns;
            if (c2 < NC) a2 += qs[c2] * ns;
        }
        float* od = Out + b * out_bs + (long long)d * NC;
        a1 += bias[c1];
        if (RELU) a1 = fmaxf(a1, 0.f);
        od[c1] = a1;
        if (c2 < NC) {
            a2 += bias[c2];
            if (RELU) a2 = fmaxf(a2, 0.f);
            od[c2] = a2;
        }
    }
}

// ---------------------------------------------------------------------------
static inline int ceil_div(long long a, int b) { return (int)((a + b - 1) / b); }

extern "C" void kernel_launch(void* const* d_in, const int* in_sizes, int n_in,
                              void* d_out, int out_size, void* d_ws, size_t ws_size,
                              hipStream_t stream)
{
    const float* X    = (const float*)d_in[0];
    const float* GF   = (const float*)d_in[1];
    const float* MF   = (const float*)d_in[2];
    const float* emw1 = (const float*)d_in[3];
    const float* emb1 = (const float*)d_in[4];
    const float* emw2 = (const float*)d_in[5];
    const float* emb2 = (const float*)d_in[6];
    const float* egw1 = (const float*)d_in[7];
    const float* egb1 = (const float*)d_in[8];
    const float* egw2 = (const float*)d_in[9];
    const float* egb2 = (const float*)d_in[10];
    const float* pgw1 = (const float*)d_in[11];
    const float* pgb1 = (const float*)d_in[12];
    const float* pgw2 = (const float*)d_in[13];
    const float* pgb2 = (const float*)d_in[14];
    const float* dgw1 = (const float*)d_in[15];
    const float* dgb1 = (const float*)d_in[16];
    const float* dgw2 = (const float*)d_in[17];
    const float* dgb2 = (const float*)d_in[18];
    const int* enc_src = (const int*)d_in[19];
    const int* enc_dst = (const int*)d_in[20];
    const int* proc_src = (const int*)d_in[21];
    const int* proc_dst = (const int*)d_in[22];
    const int* dec_src = (const int*)d_in[23];
    const int* dec_dst = (const int*)d_in[24];
    float* out = (float*)d_out;

    // ---- workspace layout ----
    float* ws_f = (float*)d_ws;
    const long long BNH = (long long)BB * NTOT * HD;    // 19,302,912 floats
    const long long BMH = (long long)BB * NMESH * HD;   //  2,621,952 floats
    float* Abuf = ws_f;
    float* Bbuf = Abuf + BNH;
    float* mw   = Bbuf + BNH;
    float* m1   = mw + BMH;
    float* dinv_enc  = m1 + BMH;            // [NTOT]
    float* dinv_proc = dinv_enc + NTOT;     // [NMESH]
    float* dinv_dec  = dinv_proc + NMESH;   // [NTOT]
    long long fcnt = 2 * BNH + 2 * BMH + (long long)(NTOT + NMESH + NTOT);
    fcnt = (fcnt + 3) & ~3LL;               // 16B align
    int* ip = (int*)(ws_f + fcnt);
    // zeroed region (one pass): cnt+fill for all 3 graphs
    int* cnt_enc  = ip;                    // NTOT
    int* fill_enc = cnt_enc + NTOT;        // NTOT
    int* cnt_proc = fill_enc + NTOT;       // NMESH
    int* fill_proc= cnt_proc + NMESH;      // NMESH
    int* cnt_dec  = fill_proc + NMESH;     // NTOT
    int* fill_dec = cnt_dec + NTOT;        // NTOT
    const long long ZERON = 4LL * NTOT + 2LL * NMESH;
    int* row_enc  = fill_dec + NTOT;       // NTOT
    int* row_proc = row_enc + NTOT;        // NMESH
    int* row_dec  = row_proc + NMESH;      // NTOT
    int* col_enc  = row_dec + NTOT;        // NE_ENC
    int* col_proc = col_enc + NE_ENC;      // NE_PROC
    int* col_dec  = col_proc + NE_PROC;    // NE_DEC
    long long icnt = ZERON + 2LL * NTOT + NMESH + NE_ENC + NE_PROC + NE_DEC;
    icnt = (icnt + 7) & ~7LL;
    short* wt = (short*)(ip + icnt);

    // WT (transposed, split) storage: [NP][KP] bf16 each for hi and lo
    const int KP1 = 160, NP1 = 128;         // emw1: K=159 -> pad 160
    const int KPH = 128, NPH = 128;         // 128x128 weights
    const int NPO = 80;                     // dgw2: NOUT=78 -> pad 80
    short* wt_emw1_h = wt;                      short* wt_emw1_l = wt_emw1_h + NP1 * KP1;
    short* wt_emw2_h = wt_emw1_l + NP1 * KP1;   short* wt_emw2_l = wt_emw2_h + NPH * KPH;
    short* wt_egw1_h = wt_emw2_l + NPH * KPH;   short* wt_egw1_l = wt_egw1_h + NPH * KPH;
    short* wt_egw2_h = wt_egw1_l + NPH * KPH;   short* wt_egw2_l = wt_egw2_h + NPH * KPH;
    short* wt_pgw1_h = wt_egw2_l + NPH * KPH;   short* wt_pgw1_l = wt_pgw1_h + NPH * KPH;
    short* wt_pgw2_h = wt_pgw1_l + NPH * KPH;   short* wt_pgw2_l = wt_pgw2_h + NPH * KPH;
    short* wt_dgw1_h = wt_pgw2_l + NPH * KPH;   short* wt_dgw1_l = wt_dgw1_h + NPH * KPH;
    short* wt_dgw2_h = wt_dgw1_l + NPH * KPH;   short* wt_dgw2_l = wt_dgw2_h + NPO * KPH;

    // ---- weight prep ----
    wprep_kernel<<<ceil_div(NP1 * KP1, 256), 256, 0, stream>>>(emw1, KENC, HD, wt_emw1_h, wt_emw1_l, KP1, NP1);
    wprep_kernel<<<ceil_div(NPH * KPH, 256), 256, 0, stream>>>(emw2, HD, HD, wt_emw2_h, wt_emw2_l, KPH, NPH);
    wprep_kernel<<<ceil_div(NPH * KPH, 256), 256, 0, stream>>>(egw1, HD, HD, wt_egw1_h, wt_egw1_l, KPH, NPH);
    wprep_kernel<<<ceil_div(NPH * KPH, 256), 256, 0, stream>>>(egw2, HD, HD, wt_egw2_h, wt_egw2_l, KPH, NPH);
    wprep_kernel<<<ceil_div(NPH * KPH, 256), 256, 0, stream>>>(pgw1, HD, HD, wt_pgw1_h, wt_pgw1_l, KPH, NPH);
    wprep_kernel<<<ceil_div(NPH * KPH, 256), 256, 0, stream>>>(pgw2, HD, HD, wt_pgw2_h, wt_pgw2_l, KPH, NPH);
    wprep_kernel<<<ceil_div(NPH * KPH, 256), 256, 0, stream>>>(dgw1, HD, HD, wt_dgw1_h, wt_dgw1_l, KPH, NPH);
    wprep_kernel<<<ceil_div(NPO * KPH, 256), 256, 0, stream>>>(dgw2, HD, OUTD, wt_dgw2_h, wt_dgw2_l, KPH, NPO);

    // ---- CSR build (zero -> counts -> rowptr -> dinv -> fill) ----
    zero_kernel<<<ceil_div(ZERON, 256), 256, 0, stream>>>(cnt_enc, (int)ZERON);
    count_kernel<<<ceil_div(NE_ENC, 256), 256, 0, stream>>>(enc_dst, cnt_enc, NE_ENC);
    count_kernel<<<ceil_div(NE_PROC, 256), 256, 0, stream>>>(proc_dst, cnt_proc, NE_PROC);
    count_kernel<<<ceil_div(NE_DEC, 256), 256, 0, stream>>>(dec_dst, cnt_dec, NE_DEC);
    scan_kernel<<<1, 1024, 0, stream>>>(cnt_enc, row_enc, NTOT);
    scan_kernel<<<1, 1024, 0, stream>>>(cnt_proc, row_proc, NMESH);
    scan_kernel<<<1, 1024, 0, stream>>>(cnt_dec, row_dec, NTOT);
    dinv_kernel<<<ceil_div(NTOT, 256), 256, 0, stream>>>(cnt_enc, dinv_enc, NTOT);
    dinv_kernel<<<ceil_div(NMESH, 256), 256, 0, stream>>>(cnt_proc, dinv_proc, NMESH);
    dinv_kernel<<<ceil_div(NTOT, 256), 256, 0, stream>>>(cnt_dec, dinv_dec, NTOT);
    fillcsr_kernel<<<ceil_div(NE_ENC, 256), 256, 0, stream>>>(enc_src, enc_dst, row_enc, fill_enc, col_enc, NE_ENC);
    fillcsr_kernel<<<ceil_div(NE_PROC, 256), 256, 0, stream>>>(proc_src, proc_dst, row_proc, fill_proc, col_proc, NE_PROC);
    fillcsr_kernel<<<ceil_div(NE_DEC, 256), 256, 0, stream>>>(dec_src, dec_dst, row_dec, fill_dec, col_dec, NE_DEC);

    const int ROWS_N = BB * NTOT;                 // 150804
    const int ROWS_M = BB * NMESH;                // 20484
    const int GB_N = ceil_div(ROWS_N, 64);
    const int GB_M = ceil_div(ROWS_M, 64);
    const long long NH_BS = (long long)NTOT * HD;
    const long long MH_BS = (long long)NMESH * HD;
    const int GA_N = ceil_div(NTOT * BB, 4);      // gather blocks, all nodes
    const int GA_M = ceil_div(NMESH * BB, 4);
    const int GA_G = ceil_div(NGRID * BB, 4);

    // ---- encoder MLP ----
    gemm_mfma<160, HD, 1, 1><<<GB_N, 256, 0, stream>>>(
        nullptr, 0, nullptr, 0, 0, X, GF, MF, wt_emw1_h, wt_emw1_l,
        emb1, Abuf, NH_BS, NTOT, ROWS_N);
    gemm_mfma<HD, HD, 0, 0><<<GB_N, 256, 0, stream>>>(
        Abuf, NH_BS, nullptr, 0, 0, nullptr, nullptr, nullptr, wt_emw2_h, wt_emw2_l,
        emb2, Abuf, NH_BS, NTOT, ROWS_N);

    // ---- encoder GCN conv 1 (relu) ----
    gemm_mfma<HD, HD, 0, 0><<<GB_N, 256, 0, stream>>>(
        Abuf, NH_BS, nullptr, 0, 0, nullptr, nullptr, nullptr, wt_egw1_h, wt_egw1_l,
        nullptr, Bbuf, NH_BS, NTOT, ROWS_N);
    gather_kernel<HD, 1><<<GA_N, 256, 0, stream>>>(
        Bbuf, NH_BS, dinv_enc, cnt_enc, row_enc, col_enc, egb1, Abuf, NH_BS, NTOT);

    // ---- encoder GCN conv 2 (no relu) -> h2 in Abuf ----
    gemm_mfma<HD, HD, 0, 0><<<GB_N, 256, 0, stream>>>(
        Abuf, NH_BS, nullptr, 0, 0, nullptr, nullptr, nullptr, wt_egw2_h, wt_egw2_l,
        nullptr, Bbuf, NH_BS, NTOT, ROWS_N);
    gather_kernel<HD, 0><<<GA_N, 256, 0, stream>>>(
        Bbuf, NH_BS, dinv_enc, cnt_enc, row_enc, col_enc, egb2, Abuf, NH_BS, NTOT);

    // ---- processor GCN conv 1 on mesh rows of h2 (relu) ----
    gemm_mfma<HD, HD, 0, 0><<<GB_M, 256, 0, stream>>>(
        Abuf + (long long)NGRID * HD, NH_BS, nullptr, 0, 0, nullptr, nullptr, nullptr,
        wt_pgw1_h, wt_pgw1_l, nullptr, mw, MH_BS, NMESH, ROWS_M);
    gather_kernel<HD, 1><<<GA_M, 256, 0, stream>>>(
        mw, MH_BS, dinv_proc, cnt_proc, row_proc, col_proc, pgb1, m1, MH_BS, NMESH);

    // ---- processor GCN conv 2 (no relu) -> m2 (:= m1, ping-pong) ----
    gemm_mfma<HD, HD, 0, 0><<<GB_M, 256, 0, stream>>>(
        m1, MH_BS, nullptr, 0, 0, nullptr, nullptr, nullptr, wt_pgw2_h, wt_pgw2_l,
        nullptr, mw, MH_BS, NMESH, ROWS_M);
    gather_kernel<HD, 0><<<GA_M, 256, 0, stream>>>(
        mw, MH_BS, dinv_proc, cnt_proc, row_proc, col_proc, pgb2, m1, MH_BS, NMESH);

    // ---- decoder GCN conv 1 over pf = [grid rows of Abuf | m1] (relu) ----
    gemm_mfma<HD, HD, 2, 0><<<GB_N, 256, 0, stream>>>(
        Abuf, NH_BS, m1, MH_BS, NGRID, nullptr, nullptr, nullptr, wt_dgw1_h, wt_dgw1_l,
        nullptr, Bbuf, NH_BS, NTOT, ROWS_N);
    gather_kernel<HD, 1><<<GA_N, 256, 0, stream>>>(
        Bbuf, NH_BS, dinv_dec, cnt_dec, row_dec, col_dec, dgb1, Abuf, NH_BS, NTOT);

    // ---- decoder GCN conv 2 -> d_out (grid rows only) ----
    const long long NO_BS = (long long)NTOT * OUTD;
    const long long GO_BS = (long long)NGRID * OUTD;
    gemm_mfma<HD, OUTD, 0, 0><<<GB_N, 256, 0, stream>>>(
        Abuf, NH_BS, nullptr, 0, 0, nullptr, nullptr, nullptr, wt_dgw2_h, wt_dgw2_l,
        nullptr, Bbuf, NO_BS, NTOT, ROWS_N);
    gather_kernel<OUTD, 0><<<GA_G, 256, 0, stream>>>(
        Bbuf, NO_BS, dinv_dec, cnt_dec, row_dec, col_dec, dgb2, out, GO_BS, NGRID);
}

// Round 8
// 1140.159 us; speedup vs baseline: 1.7615x; 1.2279x over previous
//
#include <hip/hip_runtime.h>
#include <hip/hip_bf16.h>

// Problem constants (from reference)
#define NGRID  65160
#define NMESH  10242
#define NTOT   75402      // NGRID + NMESH
#define FEAT   156
#define FI_    3
#define KENC   159        // FEAT + FI_
#define HD     128
#define OUTD   78
#define BB     2
#define NE_ENC 130320
#define NE_PROC 81920
#define NE_DEC 195480

typedef __attribute__((ext_vector_type(8))) short bf16x8;
typedef __attribute__((ext_vector_type(4))) float f32x4;

__device__ __forceinline__ short bf16_rtn(float v) {
    unsigned u = __builtin_bit_cast(unsigned, v);
    u += 0x7FFFu + ((u >> 16) & 1u);
    return (short)(u >> 16);
}
__device__ __forceinline__ float bf16_f32(short s) {
    unsigned u = ((unsigned)(unsigned short)s) << 16;
    return __builtin_bit_cast(float, u);
}

// ---------------------------------------------------------------------------
// Weight prep: W[K][N] f32 -> WT_hi/WT_lo [NP][KP] bf16 (transposed, split,
// zero-padded). Split: w = hi + lo with hi = bf16(w), lo = bf16(w - hi).
// ---------------------------------------------------------------------------
__global__ void wprep_kernel(const float* __restrict__ W, int K, int Nc,
                             short* __restrict__ WTh, short* __restrict__ WTl,
                             int KP, int NP)
{
    int idx = blockIdx.x * 256 + threadIdx.x;
    if (idx >= KP * NP) return;
    int c = idx / KP;
    int k = idx - c * KP;
    float v = (k < K && c < Nc) ? W[k * Nc + c] : 0.0f;
    short h = bf16_rtn(v);
    WTh[idx] = h;
    WTl[idx] = bf16_rtn(v - bf16_f32(h));
}

__global__ void zero_kernel(int* __restrict__ p, int n) {
    int i = blockIdx.x * 256 + threadIdx.x;
    if (i < n) p[i] = 0;
}

// ---------------------------------------------------------------------------
// CSR build: count (int atomics) -> 3-pass hierarchical exclusive scan -> fill.
// dinv[i] = rsqrt(1 + in_degree[i])  (self-loop contributes 1).
// ---------------------------------------------------------------------------
__global__ void count_kernel(const int* __restrict__ dst, int* __restrict__ cnt, int ne) {
    int e = blockIdx.x * 256 + threadIdx.x;
    if (e < ne) atomicAdd(&cnt[dst[e]], 1);
}

// pass 1: per-block (1024 elems) local exclusive scan + block sum
__global__ __launch_bounds__(256)
void scan1_kernel(const int* __restrict__ in, int* __restrict__ out,
                  int* __restrict__ bsum, int n)
{
    __shared__ int ws[256];
    const int t = threadIdx.x;
    const int base = blockIdx.x * 1024 + t * 4;
    int v[4], s = 0;
#pragma unroll
    for (int j = 0; j < 4; ++j) {
        int i = base + j;
        v[j] = (i < n) ? in[i] : 0;
        s += v[j];
    }
    ws[t] = s;
    __syncthreads();
    for (int off = 1; off < 256; off <<= 1) {
        int x = (t >= off) ? ws[t - off] : 0;
        __syncthreads();
        ws[t] += x;
        __syncthreads();
    }
    int excl = ws[t] - s;
#pragma unroll
    for (int j = 0; j < 4; ++j) {
        int i = base + j;
        if (i < n) out[i] = excl;
        excl += v[j];
    }
    if (t == 255) bsum[blockIdx.x] = ws[255];
}

// pass 2: exclusive scan of block sums (nb <= 256), single block
__global__ __launch_bounds__(256)
void scan2_kernel(int* __restrict__ bsum, int nb)
{
    __shared__ int ws[256];
    const int t = threadIdx.x;
    int s = (t < nb) ? bsum[t] : 0;
    ws[t] = s;
    __syncthreads();
    for (int off = 1; off < 256; off <<= 1) {
        int x = (t >= off) ? ws[t - off] : 0;
        __syncthreads();
        ws[t] += x;
        __syncthreads();
    }
    if (t < nb) bsum[t] = ws[t] - s;
}

// pass 3: add block offsets
__global__ __launch_bounds__(256)
void scan3_kernel(int* __restrict__ out, const int* __restrict__ bsum, int n)
{
    int i = blockIdx.x * 256 + threadIdx.x;
    if (i < n) out[i] += bsum[i >> 10];
}

__global__ void dinv_kernel(const int* __restrict__ cnt, float* __restrict__ dinv, int n) {
    int i = blockIdx.x * 256 + threadIdx.x;
    if (i < n) dinv[i] = rsqrtf(1.0f + (float)cnt[i]);
}

__global__ void fillcsr_kernel(const int* __restrict__ src, const int* __restrict__ dst,
                               const int* __restrict__ rowptr, int* __restrict__ fill,
                               int* __restrict__ colsrc, int ne) {
    int e = blockIdx.x * 256 + threadIdx.x;
    if (e < ne) {
        int d = dst[e];
        int pos = atomicAdd(&fill[d], 1);
        colsrc[rowptr[d] + pos] = src[e];
    }
}

// ---------------------------------------------------------------------------
// MFMA GEMM (split-bf16, ~f32 precision): Q = A @ W (+ bias, + relu)
// Block: 256 thr = 4 waves; 64 rows/block, wave w owns rows [w*16, w*16+16).
// Each wave computes 16 x NOUT via NCT 16x16 col-tiles, K in steps of 32.
// mfma_f32_16x16x32_bf16 fragment mapping:
//   A: lane l holds A[l%16][k0 + 8*(l/16) + j], j=0..7
//   B: lane l holds B[k0 + 8*(l/16) + j][l%16]  (read from WT[N][K], contiguous)
//   D: lane l, reg i -> row (l/16)*4+i, col l%16   [verified layout, learn_hip m89]
// MODE 0: A rows from A0 (stride KP floats)
// MODE 1: fused encoder concat [X | GF] / [0 | MF]  (K=159, KP=160)
// MODE 2: A from A0 (r < split) else A1 (dec concat)
// In-place A==Q is safe: each block reads only the 64 rows it writes, and all
// loads precede all stores within each wave.
// ---------------------------------------------------------------------------
template<int KP, int NOUT, int MODE, int RELU_OUT>
__global__ __launch_bounds__(256)
void gemm_mfma(const float* __restrict__ A0, long long a0_bs,
               const float* __restrict__ A1, long long a1_bs, int split,
               const float* __restrict__ Xin, const float* __restrict__ GFin,
               const float* __restrict__ MFin,
               const short* __restrict__ WTh, const short* __restrict__ WTl,
               const float* __restrict__ bias,
               float* __restrict__ Qout, long long q_bs,
               int rows_per_batch, int total_rows)
{
    constexpr int NCT = (NOUT + 15) / 16;
    const int t = threadIdx.x;
    const int w = t >> 6;
    const int l = t & 63;
    const int lane15 = l & 15;
    const int g = l >> 4;

    // Resolve this lane's A row once (fixed across the K loop)
    const int gr_a = blockIdx.x * 64 + w * 16 + lane15;
    const bool a_valid = (gr_a < total_rows);
    int b_a = 0, r_a = 0;
    const float* arow = nullptr;
    if (a_valid) {
        b_a = gr_a / rows_per_batch;
        r_a = gr_a - b_a * rows_per_batch;
        if (MODE == 0) {
            arow = A0 + b_a * a0_bs + (long long)r_a * KP;
        } else if (MODE == 2) {
            if (r_a >= split) arow = A1 + b_a * a1_bs + (long long)(r_a - split) * KP;
            else              arow = A0 + b_a * a0_bs + (long long)r_a * KP;
        }
    }

    f32x4 acc[NCT];
#pragma unroll
    for (int ct = 0; ct < NCT; ++ct) acc[ct] = (f32x4){0.f, 0.f, 0.f, 0.f};

#pragma unroll
    for (int k0 = 0; k0 < KP; k0 += 32) {
        const int kbase = k0 + g * 8;
        float av[8];
        if (MODE == 1) {
#pragma unroll
            for (int j = 0; j < 8; ++j) av[j] = 0.0f;
            if (a_valid) {
                const bool gridr = (r_a < NGRID);
                if (gridr && kbase + 8 <= FEAT) {
                    const float* xrow = Xin + ((long long)b_a * NGRID + r_a) * FEAT + kbase;
#pragma unroll
                    for (int j2 = 0; j2 < 4; ++j2) {   // rows are 8B-aligned (156 floats)
                        float2 v = *(const float2*)(xrow + j2 * 2);
                        av[j2 * 2]     = v.x;
                        av[j2 * 2 + 1] = v.y;
                    }
                } else {
#pragma unroll
                    for (int j = 0; j < 8; ++j) {
                        int k = kbase + j;
                        float v = 0.0f;
                        if (k < FEAT) {
                            if (gridr) v = Xin[((long long)b_a * NGRID + r_a) * FEAT + k];
                        } else if (k < KENC) {
                            v = gridr ? GFin[r_a * FI_ + (k - FEAT)]
                                      : MFin[(r_a - NGRID) * FI_ + (k - FEAT)];
                        }
                        av[j] = v;
                    }
                }
            }
        } else {
            if (a_valid) {
                float4 v0 = *(const float4*)(arow + kbase);
                float4 v1 = *(const float4*)(arow + kbase + 4);
                av[0] = v0.x; av[1] = v0.y; av[2] = v0.z; av[3] = v0.w;
                av[4] = v1.x; av[5] = v1.y; av[6] = v1.z; av[7] = v1.w;
            } else {
#pragma unroll
                for (int j = 0; j < 8; ++j) av[j] = 0.0f;
            }
        }

        // split f32 -> hi/lo bf16 in-register
        bf16x8 ah, al;
#pragma unroll
        for (int j = 0; j < 8; ++j) {
            float v = av[j];
            short h = bf16_rtn(v);
            ah[j] = h;
            al[j] = bf16_rtn(v - bf16_f32(h));
        }

#pragma unroll
        for (int ct = 0; ct < NCT; ++ct) {
            const long long boff = (long long)(ct * 16 + lane15) * KP + kbase;
            bf16x8 bh = *(const bf16x8*)(WTh + boff);
            bf16x8 bl = *(const bf16x8*)(WTl + boff);
            acc[ct] = __builtin_amdgcn_mfma_f32_16x16x32_bf16(ah, bh, acc[ct], 0, 0, 0);
            acc[ct] = __builtin_amdgcn_mfma_f32_16x16x32_bf16(al, bh, acc[ct], 0, 0, 0);
            acc[ct] = __builtin_amdgcn_mfma_f32_16x16x32_bf16(ah, bl, acc[ct], 0, 0, 0);
        }
    }

    // ---- epilogue: Q = acc (+bias) (+relu) ----
#pragma unroll
    for (int i = 0; i < 4; ++i) {
        const int gr = blockIdx.x * 64 + w * 16 + g * 4 + i;
        if (gr >= total_rows) continue;
        const int b = gr / rows_per_batch;
        const int r = gr - b * rows_per_batch;
        float* qrow = Qout + b * q_bs + (long long)r * NOUT;
#pragma unroll
        for (int ct = 0; ct < NCT; ++ct) {
            const int c = ct * 16 + lane15;
            if ((NOUT % 16 != 0) && c >= NOUT) continue;
            float v = acc[ct][i];
            if (bias) v += bias[c];
            if (RELU_OUT) v = fmaxf(v, 0.0f);
            qrow[c] = v;
        }
    }
}

// ---------------------------------------------------------------------------
// CSR gather aggregation (no atomics):
//   Out[b,d,:] = act( Q[b,d,:]*dinv[d]^2 + sum_e Q[b,src[e],:]*dinv[src]*dinv[d]
//                     + bias )
// One 64-lane wave per (node, batch); block = 4 waves.
// NC=128: float2 per lane (coalesced 512B per row read/write).
// NC=78:  lane covers cols {lane, lane+64 (guarded)}.
// ---------------------------------------------------------------------------
template<int NC, int RELU>
__global__ __launch_bounds__(256)
void gather_kernel(const float* __restrict__ Q, long long q_bs,
                   const float* __restrict__ dinv,
                   const int* __restrict__ cnt, const int* __restrict__ rowptr,
                   const int* __restrict__ colsrc,
                   const float* __restrict__ bias,
                   float* __restrict__ Out, long long out_bs, int out_rows)
{
    const int wv = blockIdx.x * 4 + (threadIdx.x >> 6);
    const int lane = threadIdx.x & 63;
    if (wv >= out_rows * BB) return;
    const int b = wv / out_rows;
    const int d = wv - b * out_rows;
    const float dv = dinv[d];
    const float dv2 = dv * dv;
    const int beg = rowptr[d];
    const int num = cnt[d];
    const float* Qb = Q + b * q_bs;

    if (NC == 128) {
        const int c = lane * 2;
        float2 acc = *(const float2*)(Qb + (long long)d * NC + c);
        acc.x *= dv2; acc.y *= dv2;
        for (int e = 0; e < num; ++e) {
            int s = colsrc[beg + e];
            float ns = dinv[s] * dv;
            float2 v = *(const float2*)(Qb + (long long)s * NC + c);
            acc.x += v.x * ns;
            acc.y += v.y * ns;
        }
        acc.x += bias[c]; acc.y += bias[c + 1];
        if (RELU) { acc.x = fmaxf(acc.x, 0.f); acc.y = fmaxf(acc.y, 0.f); }
        *(float2*)(Out + b * out_bs + (long long)d * NC + c) = acc;
    } else {
        const int c1 = lane, c2 = lane + 64;
        const float* qd = Qb + (long long)d * NC;
        float a1 = qd[c1] * dv2;
        float a2 = (c2 < NC) ? qd[c2] * dv2 : 0.f;
        for (int e = 0; e < num; ++e) {
            int s = colsrc[beg + e];
            float ns = dinv[s] * dv;
            const float* qs = Qb + (long long)s * NC;
            a1 += qs[c1] * ns;
            if (c2 < NC) a2 += qs[c2] * ns;
        }
        float* od = Out + b * out_bs + (long long)d * NC;
        a1 += bias[c1];
        if (RELU) a1 = fmaxf(a1, 0.f);
        od[c1] = a1;
        if (c2 < NC) {
            a2 += bias[c2];
            if (RELU) a2 = fmaxf(a2, 0.f);
            od[c2] = a2;
        }
    }
}

// ---------------------------------------------------------------------------
static inline int ceil_div(long long a, int b) { return (int)((a + b - 1) / b); }

extern "C" void kernel_launch(void* const* d_in, const int* in_sizes, int n_in,
                              void* d_out, int out_size, void* d_ws, size_t ws_size,
                              hipStream_t stream)
{
    const float* X    = (const float*)d_in[0];
    const float* GF   = (const float*)d_in[1];
    const float* MF   = (const float*)d_in[2];
    const float* emw1 = (const float*)d_in[3];
    const float* emb1 = (const float*)d_in[4];
    const float* emw2 = (const float*)d_in[5];
    const float* emb2 = (const float*)d_in[6];
    const float* egw1 = (const float*)d_in[7];
    const float* egb1 = (const float*)d_in[8];
    const float* egw2 = (const float*)d_in[9];
    const float* egb2 = (const float*)d_in[10];
    const float* pgw1 = (const float*)d_in[11];
    const float* pgb1 = (const float*)d_in[12];
    const float* pgw2 = (const float*)d_in[13];
    const float* pgb2 = (const float*)d_in[14];
    const float* dgw1 = (const float*)d_in[15];
    const float* dgb1 = (const float*)d_in[16];
    const float* dgw2 = (const float*)d_in[17];
    const float* dgb2 = (const float*)d_in[18];
    const int* enc_src = (const int*)d_in[19];
    const int* enc_dst = (const int*)d_in[20];
    const int* proc_src = (const int*)d_in[21];
    const int* proc_dst = (const int*)d_in[22];
    const int* dec_src = (const int*)d_in[23];
    const int* dec_dst = (const int*)d_in[24];
    float* out = (float*)d_out;

    // ---- workspace layout ----
    float* ws_f = (float*)d_ws;
    const long long BNH = (long long)BB * NTOT * HD;    // 19,302,912 floats
    const long long BMH = (long long)BB * NMESH * HD;   //  2,621,952 floats
    float* Abuf = ws_f;
    float* Bbuf = Abuf + BNH;
    float* mw   = Bbuf + BNH;
    float* m1   = mw + BMH;
    float* dinv_enc  = m1 + BMH;            // [NTOT]
    float* dinv_proc = dinv_enc + NTOT;     // [NMESH]
    float* dinv_dec  = dinv_proc + NMESH;   // [NTOT]
    long long fcnt = 2 * BNH + 2 * BMH + (long long)(NTOT + NMESH + NTOT);
    fcnt = (fcnt + 3) & ~3LL;               // 16B align
    int* ip = (int*)(ws_f + fcnt);
    // zeroed region (one pass): cnt+fill for all 3 graphs
    int* cnt_enc  = ip;                    // NTOT
    int* fill_enc = cnt_enc + NTOT;        // NTOT
    int* cnt_proc = fill_enc + NTOT;       // NMESH
    int* fill_proc= cnt_proc + NMESH;      // NMESH
    int* cnt_dec  = fill_proc + NMESH;     // NTOT
    int* fill_dec = cnt_dec + NTOT;        // NTOT
    const long long ZERON = 4LL * NTOT + 2LL * NMESH;
    int* row_enc  = fill_dec + NTOT;       // NTOT
    int* row_proc = row_enc + NTOT;        // NMESH
    int* row_dec  = row_proc + NMESH;      // NTOT
    int* col_enc  = row_dec + NTOT;        // NE_ENC
    int* col_proc = col_enc + NE_ENC;      // NE_PROC
    int* col_dec  = col_proc + NE_PROC;    // NE_DEC
    int* bsum_enc  = col_dec + NE_DEC;     // 256
    int* bsum_proc = bsum_enc + 256;       // 256
    int* bsum_dec  = bsum_proc + 256;      // 256
    long long icnt = ZERON + 2LL * NTOT + NMESH + NE_ENC + NE_PROC + NE_DEC + 768;
    icnt = (icnt + 7) & ~7LL;
    short* wt = (short*)(ip + icnt);

    // WT (transposed, split) storage: [NP][KP] bf16 each for hi and lo
    const int KP1 = 160, NP1 = 128;         // emw1: K=159 -> pad 160
    const int KPH = 128, NPH = 128;         // 128x128 weights
    const int NPO = 80;                     // dgw2: NOUT=78 -> pad 80
    short* wt_emw1_h = wt;                      short* wt_emw1_l = wt_emw1_h + NP1 * KP1;
    short* wt_emw2_h = wt_emw1_l + NP1 * KP1;   short* wt_emw2_l = wt_emw2_h + NPH * KPH;
    short* wt_egw1_h = wt_emw2_l + NPH * KPH;   short* wt_egw1_l = wt_egw1_h + NPH * KPH;
    short* wt_egw2_h = wt_egw1_l + NPH * KPH;   short* wt_egw2_l = wt_egw2_h + NPH * KPH;
    short* wt_pgw1_h = wt_egw2_l + NPH * KPH;   short* wt_pgw1_l = wt_pgw1_h + NPH * KPH;
    short* wt_pgw2_h = wt_pgw1_l + NPH * KPH;   short* wt_pgw2_l = wt_pgw2_h + NPH * KPH;
    short* wt_dgw1_h = wt_pgw2_l + NPH * KPH;   short* wt_dgw1_l = wt_dgw1_h + NPH * KPH;
    short* wt_dgw2_h = wt_dgw1_l + NPH * KPH;   short* wt_dgw2_l = wt_dgw2_h + NPO * KPH;

    // ---- weight prep ----
    wprep_kernel<<<ceil_div(NP1 * KP1, 256), 256, 0, stream>>>(emw1, KENC, HD, wt_emw1_h, wt_emw1_l, KP1, NP1);
    wprep_kernel<<<ceil_div(NPH * KPH, 256), 256, 0, stream>>>(emw2, HD, HD, wt_emw2_h, wt_emw2_l, KPH, NPH);
    wprep_kernel<<<ceil_div(NPH * KPH, 256), 256, 0, stream>>>(egw1, HD, HD, wt_egw1_h, wt_egw1_l, KPH, NPH);
    wprep_kernel<<<ceil_div(NPH * KPH, 256), 256, 0, stream>>>(egw2, HD, HD, wt_egw2_h, wt_egw2_l, KPH, NPH);
    wprep_kernel<<<ceil_div(NPH * KPH, 256), 256, 0, stream>>>(pgw1, HD, HD, wt_pgw1_h, wt_pgw1_l, KPH, NPH);
    wprep_kernel<<<ceil_div(NPH * KPH, 256), 256, 0, stream>>>(pgw2, HD, HD, wt_pgw2_h, wt_pgw2_l, KPH, NPH);
    wprep_kernel<<<ceil_div(NPH * KPH, 256), 256, 0, stream>>>(dgw1, HD, HD, wt_dgw1_h, wt_dgw1_l, KPH, NPH);
    wprep_kernel<<<ceil_div(NPO * KPH, 256), 256, 0, stream>>>(dgw2, HD, OUTD, wt_dgw2_h, wt_dgw2_l, KPH, NPO);

    // ---- CSR build (zero -> counts -> rowptr (3-pass scan) -> dinv -> fill) ----
    zero_kernel<<<ceil_div(ZERON, 256), 256, 0, stream>>>(cnt_enc, (int)ZERON);
    count_kernel<<<ceil_div(NE_ENC, 256), 256, 0, stream>>>(enc_dst, cnt_enc, NE_ENC);
    count_kernel<<<ceil_div(NE_PROC, 256), 256, 0, stream>>>(proc_dst, cnt_proc, NE_PROC);
    count_kernel<<<ceil_div(NE_DEC, 256), 256, 0, stream>>>(dec_dst, cnt_dec, NE_DEC);
    const int NB_N = ceil_div(NTOT, 1024);    // 74
    const int NB_M = ceil_div(NMESH, 1024);   // 11
    scan1_kernel<<<NB_N, 256, 0, stream>>>(cnt_enc, row_enc, bsum_enc, NTOT);
    scan1_kernel<<<NB_M, 256, 0, stream>>>(cnt_proc, row_proc, bsum_proc, NMESH);
    scan1_kernel<<<NB_N, 256, 0, stream>>>(cnt_dec, row_dec, bsum_dec, NTOT);
    scan2_kernel<<<1, 256, 0, stream>>>(bsum_enc, NB_N);
    scan2_kernel<<<1, 256, 0, stream>>>(bsum_proc, NB_M);
    scan2_kernel<<<1, 256, 0, stream>>>(bsum_dec, NB_N);
    scan3_kernel<<<ceil_div(NTOT, 256), 256, 0, stream>>>(row_enc, bsum_enc, NTOT);
    scan3_kernel<<<ceil_div(NMESH, 256), 256, 0, stream>>>(row_proc, bsum_proc, NMESH);
    scan3_kernel<<<ceil_div(NTOT, 256), 256, 0, stream>>>(row_dec, bsum_dec, NTOT);
    dinv_kernel<<<ceil_div(NTOT, 256), 256, 0, stream>>>(cnt_enc, dinv_enc, NTOT);
    dinv_kernel<<<ceil_div(NMESH, 256), 256, 0, stream>>>(cnt_proc, dinv_proc, NMESH);
    dinv_kernel<<<ceil_div(NTOT, 256), 256, 0, stream>>>(cnt_dec, dinv_dec, NTOT);
    fillcsr_kernel<<<ceil_div(NE_ENC, 256), 256, 0, stream>>>(enc_src, enc_dst, row_enc, fill_enc, col_enc, NE_ENC);
    fillcsr_kernel<<<ceil_div(NE_PROC, 256), 256, 0, stream>>>(proc_src, proc_dst, row_proc, fill_proc, col_proc, NE_PROC);
    fillcsr_kernel<<<ceil_div(NE_DEC, 256), 256, 0, stream>>>(dec_src, dec_dst, row_dec, fill_dec, col_dec, NE_DEC);

    const int ROWS_N = BB * NTOT;                 // 150804
    const int ROWS_M = BB * NMESH;                // 20484
    const int GB_N = ceil_div(ROWS_N, 64);
    const int GB_M = ceil_div(ROWS_M, 64);
    const long long NH_BS = (long long)NTOT * HD;
    const long long MH_BS = (long long)NMESH * HD;
    const int GA_N = ceil_div(NTOT * BB, 4);      // gather blocks, all nodes
    const int GA_M = ceil_div(NMESH * BB, 4);
    const int GA_G = ceil_div(NGRID * BB, 4);

    // ---- encoder MLP ----
    gemm_mfma<160, HD, 1, 1><<<GB_N, 256, 0, stream>>>(
        nullptr, 0, nullptr, 0, 0, X, GF, MF, wt_emw1_h, wt_emw1_l,
        emb1, Abuf, NH_BS, NTOT, ROWS_N);
    gemm_mfma<HD, HD, 0, 0><<<GB_N, 256, 0, stream>>>(
        Abuf, NH_BS, nullptr, 0, 0, nullptr, nullptr, nullptr, wt_emw2_h, wt_emw2_l,
        emb2, Abuf, NH_BS, NTOT, ROWS_N);

    // ---- encoder GCN conv 1 (relu) ----
    gemm_mfma<HD, HD, 0, 0><<<GB_N, 256, 0, stream>>>(
        Abuf, NH_BS, nullptr, 0, 0, nullptr, nullptr, nullptr, wt_egw1_h, wt_egw1_l,
        nullptr, Bbuf, NH_BS, NTOT, ROWS_N);
    gather_kernel<HD, 1><<<GA_N, 256, 0, stream>>>(
        Bbuf, NH_BS, dinv_enc, cnt_enc, row_enc, col_enc, egb1, Abuf, NH_BS, NTOT);

    // ---- encoder GCN conv 2 (no relu) -> h2 in Abuf ----
    gemm_mfma<HD, HD, 0, 0><<<GB_N, 256, 0, stream>>>(
        Abuf, NH_BS, nullptr, 0, 0, nullptr, nullptr, nullptr, wt_egw2_h, wt_egw2_l,
        nullptr, Bbuf, NH_BS, NTOT, ROWS_N);
    gather_kernel<HD, 0><<<GA_N, 256, 0, stream>>>(
        Bbuf, NH_BS, dinv_enc, cnt_enc, row_enc, col_enc, egb2, Abuf, NH_BS, NTOT);

    // ---- processor GCN conv 1 on mesh rows of h2 (relu) ----
    gemm_mfma<HD, HD, 0, 0><<<GB_M, 256, 0, stream>>>(
        Abuf + (long long)NGRID * HD, NH_BS, nullptr, 0, 0, nullptr, nullptr, nullptr,
        wt_pgw1_h, wt_pgw1_l, nullptr, mw, MH_BS, NMESH, ROWS_M);
    gather_kernel<HD, 1><<<GA_M, 256, 0, stream>>>(
        mw, MH_BS, dinv_proc, cnt_proc, row_proc, col_proc, pgb1, m1, MH_BS, NMESH);

    // ---- processor GCN conv 2 (no relu) -> m2 (:= m1, ping-pong) ----
    gemm_mfma<HD, HD, 0, 0><<<GB_M, 256, 0, stream>>>(
        m1, MH_BS, nullptr, 0, 0, nullptr, nullptr, nullptr, wt_pgw2_h, wt_pgw2_l,
        nullptr, mw, MH_BS, NMESH, ROWS_M);
    gather_kernel<HD, 0><<<GA_M, 256, 0, stream>>>(
        mw, MH_BS, dinv_proc, cnt_proc, row_proc, col_proc, pgb2, m1, MH_BS, NMESH);

    // ---- decoder GCN conv 1 over pf = [grid rows of Abuf | m1] (relu) ----
    gemm_mfma<HD, HD, 2, 0><<<GB_N, 256, 0, stream>>>(
        Abuf, NH_BS, m1, MH_BS, NGRID, nullptr, nullptr, nullptr, wt_dgw1_h, wt_dgw1_l,
        nullptr, Bbuf, NH_BS, NTOT, ROWS_N);
    gather_kernel<HD, 1><<<GA_N, 256, 0, stream>>>(
        Bbuf, NH_BS, dinv_dec, cnt_dec, row_dec, col_dec, dgb1, Abuf, NH_BS, NTOT);

    // ---- decoder GCN conv 2 -> d_out (grid rows only) ----
    const long long NO_BS = (long long)NTOT * OUTD;
    const long long GO_BS = (long long)NGRID * OUTD;
    gemm_mfma<HD, OUTD, 0, 0><<<GB_N, 256, 0, stream>>>(
        Abuf, NH_BS, nullptr, 0, 0, nullptr, nullptr, nullptr, wt_dgw2_h, wt_dgw2_l,
        nullptr, Bbuf, NO_BS, NTOT, ROWS_N);
    gather_kernel<OUTD, 0><<<GA_G, 256, 0, stream>>>(
        Bbuf, NO_BS, dinv_dec, cnt_dec, row_dec, col_dec, dgb2, out, GO_BS, NGRID);
}

// Round 10
// 1123.900 us; speedup vs baseline: 1.7870x; 1.0145x over previous
//
#include <hip/hip_runtime.h>
#include <hip/hip_bf16.h>

// Problem constants (from reference)
#define NGRID  65160
#define NMESH  10242
#define NTOT   75402      // NGRID + NMESH
#define FEAT   156
#define FI_    3
#define KENC   159        // FEAT + FI_
#define HD     128
#define OUTD   78
#define BB     2
#define NE_ENC 130320
#define NE_PROC 81920
#define NE_DEC 195480

typedef __attribute__((ext_vector_type(8))) short bf16x8;
typedef __attribute__((ext_vector_type(4))) float f32x4;

__device__ __forceinline__ short bf16_rtn(float v) {
    unsigned u = __builtin_bit_cast(unsigned, v);
    u += 0x7FFFu + ((u >> 16) & 1u);
    return (short)(u >> 16);
}
__device__ __forceinline__ float bf16_f32(short s) {
    unsigned u = ((unsigned)(unsigned short)s) << 16;
    return __builtin_bit_cast(float, u);
}

// ---------------------------------------------------------------------------
// Weight prep: W[K][N] f32 -> WT_hi/WT_lo [NP][KP] bf16 (transposed, split,
// zero-padded). Split: w = hi + lo with hi = bf16(w), lo = bf16(w - hi).
// ---------------------------------------------------------------------------
__global__ void wprep_kernel(const float* __restrict__ W, int K, int Nc,
                             short* __restrict__ WTh, short* __restrict__ WTl,
                             int KP, int NP)
{
    int idx = blockIdx.x * 256 + threadIdx.x;
    if (idx >= KP * NP) return;
    int c = idx / KP;
    int k = idx - c * KP;
    float v = (k < K && c < Nc) ? W[k * Nc + c] : 0.0f;
    short h = bf16_rtn(v);
    WTh[idx] = h;
    WTl[idx] = bf16_rtn(v - bf16_f32(h));
}

__global__ void zero_kernel(int* __restrict__ p, int n) {
    int i = blockIdx.x * 256 + threadIdx.x;
    if (i < n) p[i] = 0;
}

// ---------------------------------------------------------------------------
// CSR build: count (int atomics) -> 3-pass hierarchical exclusive scan -> fill.
// dinv[i] = rsqrt(1 + in_degree[i])  (self-loop contributes 1).
// ---------------------------------------------------------------------------
__global__ void count_kernel(const int* __restrict__ dst, int* __restrict__ cnt, int ne) {
    int e = blockIdx.x * 256 + threadIdx.x;
    if (e < ne) atomicAdd(&cnt[dst[e]], 1);
}

// pass 1: per-block (1024 elems) local exclusive scan + block sum
__global__ __launch_bounds__(256)
void scan1_kernel(const int* __restrict__ in, int* __restrict__ out,
                  int* __restrict__ bsum, int n)
{
    __shared__ int ws[256];
    const int t = threadIdx.x;
    const int base = blockIdx.x * 1024 + t * 4;
    int v[4], s = 0;
#pragma unroll
    for (int j = 0; j < 4; ++j) {
        int i = base + j;
        v[j] = (i < n) ? in[i] : 0;
        s += v[j];
    }
    ws[t] = s;
    __syncthreads();
    for (int off = 1; off < 256; off <<= 1) {
        int x = (t >= off) ? ws[t - off] : 0;
        __syncthreads();
        ws[t] += x;
        __syncthreads();
    }
    int excl = ws[t] - s;
#pragma unroll
    for (int j = 0; j < 4; ++j) {
        int i = base + j;
        if (i < n) out[i] = excl;
        excl += v[j];
    }
    if (t == 255) bsum[blockIdx.x] = ws[255];
}

// pass 2: exclusive scan of block sums (nb <= 256), single block
__global__ __launch_bounds__(256)
void scan2_kernel(int* __restrict__ bsum, int nb)
{
    __shared__ int ws[256];
    const int t = threadIdx.x;
    int s = (t < nb) ? bsum[t] : 0;
    ws[t] = s;
    __syncthreads();
    for (int off = 1; off < 256; off <<= 1) {
        int x = (t >= off) ? ws[t - off] : 0;
        __syncthreads();
        ws[t] += x;
        __syncthreads();
    }
    if (t < nb) bsum[t] = ws[t] - s;
}

// pass 3: add block offsets
__global__ __launch_bounds__(256)
void scan3_kernel(int* __restrict__ out, const int* __restrict__ bsum, int n)
{
    int i = blockIdx.x * 256 + threadIdx.x;
    if (i < n) out[i] += bsum[i >> 10];
}

__global__ void dinv_kernel(const int* __restrict__ cnt, float* __restrict__ dinv, int n) {
    int i = blockIdx.x * 256 + threadIdx.x;
    if (i < n) dinv[i] = rsqrtf(1.0f + (float)cnt[i]);
}

__global__ void fillcsr_kernel(const int* __restrict__ src, const int* __restrict__ dst,
                               const int* __restrict__ rowptr, int* __restrict__ fill,
                               int* __restrict__ colsrc, int ne) {
    int e = blockIdx.x * 256 + threadIdx.x;
    if (e < ne) {
        int d = dst[e];
        int pos = atomicAdd(&fill[d], 1);
        colsrc[rowptr[d] + pos] = src[e];
    }
}

// ---------------------------------------------------------------------------
// Register-blocked MFMA GEMM (split-bf16, ~f32 precision): Q = A@W (+bias,+relu)
// Block: 256 thr = 4 waves = RW row-waves x CW col-waves.
//   CW = (NOUTP/16)/NCW col-waves, RW = 4/CW row-waves.
//   Each wave: 64 rows (4 row-tiles of 16) x NCW*16 cols.
//   Block covers BROWS = RW*64 rows x NOUTP cols.
// K-loop outer: B frags (bh/bl for NCW cts) loaded ONCE per k-step and reused
// across 4 row-tiles -> MFMA:load = 3:1 (vs 4:3 unblocked), B traffic /4.
// mfma_f32_16x16x32_bf16 mapping: A lane l holds A[l%16][k0+8*(l/16)+j];
//   B from WT[N][K] rows (contiguous); D lane l reg i -> row (l/16)*4+i, col l%16.
// MODE 0: A rows from A0; MODE 1: fused encoder concat; MODE 2: dec concat.
// In-place A==Q safe: __syncthreads() separates all A-reads from all writes;
// blocks own disjoint row ranges.
// ---------------------------------------------------------------------------
template<int KP, int NOUTP, int NOUT, int NCW, int MODE, int RELU_OUT>
__global__ __launch_bounds__(256)
void gemm_mfma(const float* __restrict__ A0, long long a0_bs,
               const float* __restrict__ A1, long long a1_bs, int split,
               const float* __restrict__ Xin, const float* __restrict__ GFin,
               const float* __restrict__ MFin,
               const short* __restrict__ WTh, const short* __restrict__ WTl,
               const float* __restrict__ bias,
               float* __restrict__ Qout, long long q_bs,
               int rows_per_batch, int total_rows)
{
    constexpr int NCT = NOUTP / 16;
    constexpr int CW  = NCT / NCW;     // col-waves
    constexpr int RW  = 4 / CW;        // row-waves
    constexpr int BROWS = RW * 64;
    const int t = threadIdx.x;
    const int w = t >> 6;
    const int l = t & 63;
    const int lane15 = l & 15;
    const int g = l >> 4;
    const int rw = w / CW;
    const int cw = w - rw * CW;
    const int row_base = blockIdx.x * BROWS + rw * 64;
    const int ct0 = cw * NCW;

    // Per-row-tile A row resolution (4 rows per lane: m*16 + lane15)
    const float* arow[4];
    int b_a[4], r_a[4];
    bool valid[4];
#pragma unroll
    for (int m = 0; m < 4; ++m) {
        const int gr = row_base + m * 16 + lane15;
        valid[m] = (gr < total_rows);
        arow[m] = nullptr;
        b_a[m] = 0; r_a[m] = 0;
        if (valid[m]) {
            int b = gr / rows_per_batch;
            int r = gr - b * rows_per_batch;
            b_a[m] = b; r_a[m] = r;
            if (MODE == 0) {
                arow[m] = A0 + b * a0_bs + (long long)r * KP;
            } else if (MODE == 2) {
                if (r >= split) arow[m] = A1 + b * a1_bs + (long long)(r - split) * KP;
                else            arow[m] = A0 + b * a0_bs + (long long)r * KP;
            }
        }
    }

    f32x4 acc[4][NCW];
#pragma unroll
    for (int m = 0; m < 4; ++m)
#pragma unroll
        for (int ct = 0; ct < NCW; ++ct) acc[m][ct] = (f32x4){0.f, 0.f, 0.f, 0.f};

#pragma unroll
    for (int k0 = 0; k0 < KP; k0 += 32) {
        const int kbase = k0 + g * 8;
        // ---- load B fragments once per k-step ----
        bf16x8 bh[NCW], bl[NCW];
#pragma unroll
        for (int ct = 0; ct < NCW; ++ct) {
            const long long boff = (long long)((ct0 + ct) * 16 + lane15) * KP + kbase;
            bh[ct] = *(const bf16x8*)(WTh + boff);
            bl[ct] = *(const bf16x8*)(WTl + boff);
        }
        // ---- 4 row-tiles reuse B ----
#pragma unroll
        for (int m = 0; m < 4; ++m) {
            float av[8];
            if (MODE == 1) {
#pragma unroll
                for (int j = 0; j < 8; ++j) av[j] = 0.0f;
                if (valid[m]) {
                    const bool gridr = (r_a[m] < NGRID);
                    if (gridr && kbase + 8 <= FEAT) {
                        const float* xrow = Xin + ((long long)b_a[m] * NGRID + r_a[m]) * FEAT + kbase;
#pragma unroll
                        for (int j2 = 0; j2 < 4; ++j2) {   // rows are 8B-aligned (156 floats)
                            float2 v = *(const float2*)(xrow + j2 * 2);
                            av[j2 * 2]     = v.x;
                            av[j2 * 2 + 1] = v.y;
                        }
                    } else {
#pragma unroll
                        for (int j = 0; j < 8; ++j) {
                            int k = kbase + j;
                            float v = 0.0f;
                            if (k < FEAT) {
                                if (gridr) v = Xin[((long long)b_a[m] * NGRID + r_a[m]) * FEAT + k];
                            } else if (k < KENC) {
                                v = gridr ? GFin[r_a[m] * FI_ + (k - FEAT)]
                                          : MFin[(r_a[m] - NGRID) * FI_ + (k - FEAT)];
                            }
                            av[j] = v;
                        }
                    }
                }
            } else {
                if (valid[m]) {
                    float4 v0 = *(const float4*)(arow[m] + kbase);
                    float4 v1 = *(const float4*)(arow[m] + kbase + 4);
                    av[0] = v0.x; av[1] = v0.y; av[2] = v0.z; av[3] = v0.w;
                    av[4] = v1.x; av[5] = v1.y; av[6] = v1.z; av[7] = v1.w;
                } else {
#pragma unroll
                    for (int j = 0; j < 8; ++j) av[j] = 0.0f;
                }
            }

            // split f32 -> hi/lo bf16 in-register
            bf16x8 ah, al;
#pragma unroll
            for (int j = 0; j < 8; ++j) {
                float v = av[j];
                short h = bf16_rtn(v);
                ah[j] = h;
                al[j] = bf16_rtn(v - bf16_f32(h));
            }

#pragma unroll
            for (int ct = 0; ct < NCW; ++ct) {
                acc[m][ct] = __builtin_amdgcn_mfma_f32_16x16x32_bf16(ah, bh[ct], acc[m][ct], 0, 0, 0);
                acc[m][ct] = __builtin_amdgcn_mfma_f32_16x16x32_bf16(al, bh[ct], acc[m][ct], 0, 0, 0);
                acc[m][ct] = __builtin_amdgcn_mfma_f32_16x16x32_bf16(ah, bl[ct], acc[m][ct], 0, 0, 0);
            }
        }
    }

    // In-place safety: all A-reads complete before any Q-writes (col-waves
    // of the same row range read full rows).
    __syncthreads();

    // ---- epilogue: Q = acc (+bias) (+relu) ----
#pragma unroll
    for (int m = 0; m < 4; ++m) {
#pragma unroll
        for (int i = 0; i < 4; ++i) {
            const int gr = row_base + m * 16 + g * 4 + i;
            if (gr >= total_rows) continue;
            const int b = gr / rows_per_batch;
            const int r = gr - b * rows_per_batch;
            float* qrow = Qout + b * q_bs + (long long)r * NOUT;
#pragma unroll
            for (int ct = 0; ct < NCW; ++ct) {
                const int c = (ct0 + ct) * 16 + lane15;
                if ((NOUT != NOUTP) && c >= NOUT) continue;
                float v = acc[m][ct][i];
                if (bias) v += bias[c];
                if (RELU_OUT) v = fmaxf(v, 0.0f);
                qrow[c] = v;
            }
        }
    }
}

// ---------------------------------------------------------------------------
// CSR gather aggregation (no atomics):
//   Out[b,d,:] = act( Q[b,d,:]*dinv[d]^2 + sum_e Q[b,src[e],:]*dinv[src]*dinv[d]
//                     + bias )
// One 64-lane wave per (node, batch); block = 4 waves.
// ---------------------------------------------------------------------------
template<int NC, int RELU>
__global__ __launch_bounds__(256)
void gather_kernel(const float* __restrict__ Q, long long q_bs,
                   const float* __restrict__ dinv,
                   const int* __restrict__ cnt, const int* __restrict__ rowptr,
                   const int* __restrict__ colsrc,
                   const float* __restrict__ bias,
                   float* __restrict__ Out, long long out_bs, int out_rows)
{
    const int wv = blockIdx.x * 4 + (threadIdx.x >> 6);
    const int lane = threadIdx.x & 63;
    if (wv >= out_rows * BB) return;
    const int b = wv / out_rows;
    const int d = wv - b * out_rows;
    const float dv = dinv[d];
    const float dv2 = dv * dv;
    const int beg = rowptr[d];
    const int num = cnt[d];
    const float* Qb = Q + b * q_bs;

    if (NC == 128) {
        const int c = lane * 2;
        float2 acc = *(const float2*)(Qb + (long long)d * NC + c);
        acc.x *= dv2; acc.y *= dv2;
        for (int e = 0; e < num; ++e) {
            int s = colsrc[beg + e];
            float ns = dinv[s] * dv;
            float2 v = *(const float2*)(Qb + (long long)s * NC + c);
            acc.x += v.x * ns;
            acc.y += v.y * ns;
        }
        acc.x += bias[c]; acc.y += bias[c + 1];
        if (RELU) { acc.x = fmaxf(acc.x, 0.f); acc.y = fmaxf(acc.y, 0.f); }
        *(float2*)(Out + b * out_bs + (long long)d * NC + c) = acc;
    } else {
        const int c1 = lane, c2 = lane + 64;
        const float* qd = Qb + (long long)d * NC;
        float a1 = qd[c1] * dv2;
        float a2 = (c2 < NC) ? qd[c2] * dv2 : 0.f;
        for (int e = 0; e < num; ++e) {
            int s = colsrc[beg + e];
            float ns = dinv[s] * dv;
            const float* qs = Qb + (long long)s * NC;
            a1 += qs[c1] * ns;
            if (c2 < NC) a2 += qs[c2] * ns;
        }
        float* od = Out + b * out_bs + (long long)d * NC;
        a1 += bias[c1];
        if (RELU) a1 = fmaxf(a1, 0.f);
        od[c1] = a1;
        if (c2 < NC) {
            a2 += bias[c2];
            if (RELU) a2 = fmaxf(a2, 0.f);
            od[c2] = a2;
        }
    }
}

// ---------------------------------------------------------------------------
static inline int ceil_div(long long a, int b) { return (int)((a + b - 1) / b); }

extern "C" void kernel_launch(void* const* d_in, const int* in_sizes, int n_in,
                              void* d_out, int out_size, void* d_ws, size_t ws_size,
                              hipStream_t stream)
{
    const float* X    = (const float*)d_in[0];
    const float* GF   = (const float*)d_in[1];
    const float* MF   = (const float*)d_in[2];
    const float* emw1 = (const float*)d_in[3];
    const float* emb1 = (const float*)d_in[4];
    const float* emw2 = (const float*)d_in[5];
    const float* emb2 = (const float*)d_in[6];
    const float* egw1 = (const float*)d_in[7];
    const float* egb1 = (const float*)d_in[8];
    const float* egw2 = (const float*)d_in[9];
    const float* egb2 = (const float*)d_in[10];
    const float* pgw1 = (const float*)d_in[11];
    const float* pgb1 = (const float*)d_in[12];
    const float* pgw2 = (const float*)d_in[13];
    const float* pgb2 = (const float*)d_in[14];
    const float* dgw1 = (const float*)d_in[15];
    const float* dgb1 = (const float*)d_in[16];
    const float* dgw2 = (const float*)d_in[17];
    const float* dgb2 = (const float*)d_in[18];
    const int* enc_src = (const int*)d_in[19];
    const int* enc_dst = (const int*)d_in[20];
    const int* proc_src = (const int*)d_in[21];
    const int* proc_dst = (const int*)d_in[22];
    const int* dec_src = (const int*)d_in[23];
    const int* dec_dst = (const int*)d_in[24];
    float* out = (float*)d_out;

    // ---- workspace layout ----
    float* ws_f = (float*)d_ws;
    const long long BNH = (long long)BB * NTOT * HD;    // 19,302,912 floats
    const long long BMH = (long long)BB * NMESH * HD;   //  2,621,952 floats
    float* Abuf = ws_f;
    float* Bbuf = Abuf + BNH;
    float* mw   = Bbuf + BNH;
    float* m1   = mw + BMH;
    float* dinv_enc  = m1 + BMH;            // [NTOT]
    float* dinv_proc = dinv_enc + NTOT;     // [NMESH]
    float* dinv_dec  = dinv_proc + NMESH;   // [NTOT]
    long long fcnt = 2 * BNH + 2 * BMH + (long long)(NTOT + NMESH + NTOT);
    fcnt = (fcnt + 3) & ~3LL;               // 16B align
    int* ip = (int*)(ws_f + fcnt);
    // zeroed region (one pass): cnt+fill for all 3 graphs
    int* cnt_enc  = ip;                    // NTOT
    int* fill_enc = cnt_enc + NTOT;        // NTOT
    int* cnt_proc = fill_enc + NTOT;       // NMESH
    int* fill_proc= cnt_proc + NMESH;      // NMESH
    int* cnt_dec  = fill_proc + NMESH;     // NTOT
    int* fill_dec = cnt_dec + NTOT;        // NTOT
    const long long ZERON = 4LL * NTOT + 2LL * NMESH;
    int* row_enc  = fill_dec + NTOT;       // NTOT
    int* row_proc = row_enc + NTOT;        // NMESH
    int* row_dec  = row_proc + NMESH;      // NTOT
    int* col_enc  = row_dec + NTOT;        // NE_ENC
    int* col_proc = col_enc + NE_ENC;      // NE_PROC
    int* col_dec  = col_proc + NE_PROC;    // NE_DEC
    int* bsum_enc  = col_dec + NE_DEC;     // 256
    int* bsum_proc = bsum_enc + 256;       // 256
    int* bsum_dec  = bsum_proc + 256;      // 256
    long long icnt = ZERON + 2LL * NTOT + NMESH + NE_ENC + NE_PROC + NE_DEC + 768;
    icnt = (icnt + 7) & ~7LL;
    short* wt = (short*)(ip + icnt);

    // WT (transposed, split) storage: [NP][KP] bf16 each for hi and lo
    const int KP1 = 160, NP1 = 128;         // emw1: K=159 -> pad 160
    const int KPH = 128, NPH = 128;         // 128x128 weights
    const int NPO = 80;                     // dgw2: NOUT=78 -> pad 80
    short* wt_emw1_h = wt;                      short* wt_emw1_l = wt_emw1_h + NP1 * KP1;
    short* wt_emw2_h = wt_emw1_l + NP1 * KP1;   short* wt_emw2_l = wt_emw2_h + NPH * KPH;
    short* wt_egw1_h = wt_emw2_l + NPH * KPH;   short* wt_egw1_l = wt_egw1_h + NPH * KPH;
    short* wt_egw2_h = wt_egw1_l + NPH * KPH;   short* wt_egw2_l = wt_egw2_h + NPH * KPH;
    short* wt_pgw1_h = wt_egw2_l + NPH * KPH;   short* wt_pgw1_l = wt_pgw1_h + NPH * KPH;
    short* wt_pgw2_h = wt_pgw1_l + NPH * KPH;   short* wt_pgw2_l = wt_pgw2_h + NPH * KPH;
    short* wt_dgw1_h = wt_pgw2_l + NPH * KPH;   short* wt_dgw1_l = wt_dgw1_h + NPH * KPH;
    short* wt_dgw2_h = wt_dgw1_l + NPH * KPH;   short* wt_dgw2_l = wt_dgw2_h + NPO * KPH;

    // ---- weight prep ----
    wprep_kernel<<<ceil_div(NP1 * KP1, 256), 256, 0, stream>>>(emw1, KENC, HD, wt_emw1_h, wt_emw1_l, KP1, NP1);
    wprep_kernel<<<ceil_div(NPH * KPH, 256), 256, 0, stream>>>(emw2, HD, HD, wt_emw2_h, wt_emw2_l, KPH, NPH);
    wprep_kernel<<<ceil_div(NPH * KPH, 256), 256, 0, stream>>>(egw1, HD, HD, wt_egw1_h, wt_egw1_l, KPH, NPH);
    wprep_kernel<<<ceil_div(NPH * KPH, 256), 256, 0, stream>>>(egw2, HD, HD, wt_egw2_h, wt_egw2_l, KPH, NPH);
    wprep_kernel<<<ceil_div(NPH * KPH, 256), 256, 0, stream>>>(pgw1, HD, HD, wt_pgw1_h, wt_pgw1_l, KPH, NPH);
    wprep_kernel<<<ceil_div(NPH * KPH, 256), 256, 0, stream>>>(pgw2, HD, HD, wt_pgw2_h, wt_pgw2_l, KPH, NPH);
    wprep_kernel<<<ceil_div(NPH * KPH, 256), 256, 0, stream>>>(dgw1, HD, HD, wt_dgw1_h, wt_dgw1_l, KPH, NPH);
    wprep_kernel<<<ceil_div(NPO * KPH, 256), 256, 0, stream>>>(dgw2, HD, OUTD, wt_dgw2_h, wt_dgw2_l, KPH, NPO);

    // ---- CSR build (zero -> counts -> rowptr (3-pass scan) -> dinv -> fill) ----
    zero_kernel<<<ceil_div(ZERON, 256), 256, 0, stream>>>(cnt_enc, (int)ZERON);
    count_kernel<<<ceil_div(NE_ENC, 256), 256, 0, stream>>>(enc_dst, cnt_enc, NE_ENC);
    count_kernel<<<ceil_div(NE_PROC, 256), 256, 0, stream>>>(proc_dst, cnt_proc, NE_PROC);
    count_kernel<<<ceil_div(NE_DEC, 256), 256, 0, stream>>>(dec_dst, cnt_dec, NE_DEC);
    const int NB_N = ceil_div(NTOT, 1024);    // 74
    const int NB_M = ceil_div(NMESH, 1024);   // 11
    scan1_kernel<<<NB_N, 256, 0, stream>>>(cnt_enc, row_enc, bsum_enc, NTOT);
    scan1_kernel<<<NB_M, 256, 0, stream>>>(cnt_proc, row_proc, bsum_proc, NMESH);
    scan1_kernel<<<NB_N, 256, 0, stream>>>(cnt_dec, row_dec, bsum_dec, NTOT);
    scan2_kernel<<<1, 256, 0, stream>>>(bsum_enc, NB_N);
    scan2_kernel<<<1, 256, 0, stream>>>(bsum_proc, NB_M);
    scan2_kernel<<<1, 256, 0, stream>>>(bsum_dec, NB_N);
    scan3_kernel<<<ceil_div(NTOT, 256), 256, 0, stream>>>(row_enc, bsum_enc, NTOT);
    scan3_kernel<<<ceil_div(NMESH, 256), 256, 0, stream>>>(row_proc, bsum_proc, NMESH);
    scan3_kernel<<<ceil_div(NTOT, 256), 256, 0, stream>>>(row_dec, bsum_dec, NTOT);
    dinv_kernel<<<ceil_div(NTOT, 256), 256, 0, stream>>>(cnt_enc, dinv_enc, NTOT);
    dinv_kernel<<<ceil_div(NMESH, 256), 256, 0, stream>>>(cnt_proc, dinv_proc, NMESH);
    dinv_kernel<<<ceil_div(NTOT, 256), 256, 0, stream>>>(cnt_dec, dinv_dec, NTOT);
    fillcsr_kernel<<<ceil_div(NE_ENC, 256), 256, 0, stream>>>(enc_src, enc_dst, row_enc, fill_enc, col_enc, NE_ENC);
    fillcsr_kernel<<<ceil_div(NE_PROC, 256), 256, 0, stream>>>(proc_src, proc_dst, row_proc, fill_proc, col_proc, NE_PROC);
    fillcsr_kernel<<<ceil_div(NE_DEC, 256), 256, 0, stream>>>(dec_src, dec_dst, row_dec, fill_dec, col_dec, NE_DEC);

    const int ROWS_N = BB * NTOT;                 // 150804
    const int ROWS_M = BB * NMESH;                // 20484
    const int GB_N128 = ceil_div(ROWS_N, 128);    // 128-row blocks (HD gemms)
    const int GB_M128 = ceil_div(ROWS_M, 128);
    const int GB_N256 = ceil_div(ROWS_N, 256);    // 256-row blocks (OUTD gemm)
    const long long NH_BS = (long long)NTOT * HD;
    const long long MH_BS = (long long)NMESH * HD;
    const int GA_N = ceil_div(NTOT * BB, 4);      // gather blocks, all nodes
    const int GA_M = ceil_div(NMESH * BB, 4);
    const int GA_G = ceil_div(NGRID * BB, 4);

    // ---- encoder MLP ----
    gemm_mfma<160, HD, HD, 4, 1, 1><<<GB_N128, 256, 0, stream>>>(
        nullptr, 0, nullptr, 0, 0, X, GF, MF, wt_emw1_h, wt_emw1_l,
        emb1, Abuf, NH_BS, NTOT, ROWS_N);
    gemm_mfma<HD, HD, HD, 4, 0, 0><<<GB_N128, 256, 0, stream>>>(
        Abuf, NH_BS, nullptr, 0, 0, nullptr, nullptr, nullptr, wt_emw2_h, wt_emw2_l,
        emb2, Abuf, NH_BS, NTOT, ROWS_N);

    // ---- encoder GCN conv 1 (relu) ----
    gemm_mfma<HD, HD, HD, 4, 0, 0><<<GB_N128, 256, 0, stream>>>(
        Abuf, NH_BS, nullptr, 0, 0, nullptr, nullptr, nullptr, wt_egw1_h, wt_egw1_l,
        nullptr, Bbuf, NH_BS, NTOT, ROWS_N);
    gather_kernel<HD, 1><<<GA_N, 256, 0, stream>>>(
        Bbuf, NH_BS, dinv_enc, cnt_enc, row_enc, col_enc, egb1, Abuf, NH_BS, NTOT);

    // ---- encoder GCN conv 2 (no relu) -> h2 in Abuf ----
    gemm_mfma<HD, HD, HD, 4, 0, 0><<<GB_N128, 256, 0, stream>>>(
        Abuf, NH_BS, nullptr, 0, 0, nullptr, nullptr, nullptr, wt_egw2_h, wt_egw2_l,
        nullptr, Bbuf, NH_BS, NTOT, ROWS_N);
    gather_kernel<HD, 0><<<GA_N, 256, 0, stream>>>(
        Bbuf, NH_BS, dinv_enc, cnt_enc, row_enc, col_enc, egb2, Abuf, NH_BS, NTOT);

    // ---- processor GCN conv 1 on mesh rows of h2 (relu) ----
    gemm_mfma<HD, HD, HD, 4, 0, 0><<<GB_M128, 256, 0, stream>>>(
        Abuf + (long long)NGRID * HD, NH_BS, nullptr, 0, 0, nullptr, nullptr, nullptr,
        wt_pgw1_h, wt_pgw1_l, nullptr, mw, MH_BS, NMESH, ROWS_M);
    gather_kernel<HD, 1><<<GA_M, 256, 0, stream>>>(
        mw, MH_BS, dinv_proc, cnt_proc, row_proc, col_proc, pgb1, m1, MH_BS, NMESH);

    // ---- processor GCN conv 2 (no relu) ----
    gemm_mfma<HD, HD, HD, 4, 0, 0><<<GB_M128, 256, 0, stream>>>(
        m1, MH_BS, nullptr, 0, 0, nullptr, nullptr, nullptr, wt_pgw2_h, wt_pgw2_l,
        nullptr, mw, MH_BS, NMESH, ROWS_M);
    gather_kernel<HD, 0><<<GA_M, 256, 0, stream>>>(
        mw, MH_BS, dinv_proc, cnt_proc, row_proc, col_proc, pgb2, m1, MH_BS, NMESH);

    // ---- decoder GCN conv 1 over pf = [grid rows of Abuf | m1] (relu) ----
    gemm_mfma<HD, HD, HD, 4, 2, 0><<<GB_N128, 256, 0, stream>>>(
        Abuf, NH_BS, m1, MH_BS, NGRID, nullptr, nullptr, nullptr, wt_dgw1_h, wt_dgw1_l,
        nullptr, Bbuf, NH_BS, NTOT, ROWS_N);
    gather_kernel<HD, 1><<<GA_N, 256, 0, stream>>>(
        Bbuf, NH_BS, dinv_dec, cnt_dec, row_dec, col_dec, dgb1, Abuf, NH_BS, NTOT);

    // ---- decoder GCN conv 2 -> d_out (grid rows only) ----
    const long long NO_BS = (long long)NTOT * OUTD;
    const long long GO_BS = (long long)NGRID * OUTD;
    gemm_mfma<HD, 80, OUTD, 5, 0, 0><<<GB_N256, 256, 0, stream>>>(
        Abuf, NH_BS, nullptr, 0, 0, nullptr, nullptr, nullptr, wt_dgw2_h, wt_dgw2_l,
        nullptr, Bbuf, NO_BS, NTOT, ROWS_N);
    gather_kernel<OUTD, 0><<<GA_G, 256, 0, stream>>>(
        Bbuf, NO_BS, dinv_dec, cnt_dec, row_dec, col_dec, dgb2, out, GO_BS, NGRID);
}